// Round 3
// baseline (154.758 us; speedup 1.0000x reference)
//
#include <hip/hip_runtime.h>

typedef _Float16 half8  __attribute__((ext_vector_type(8)));
typedef _Float16 half4  __attribute__((ext_vector_type(4)));
typedef float    floatx4  __attribute__((ext_vector_type(4)));
typedef float    floatx16 __attribute__((ext_vector_type(16)));
typedef unsigned int uint4v __attribute__((ext_vector_type(4)));

constexpr int B_ = 2, S_ = 2048, D_ = 1024, H_ = 16, M_ = 4096;
constexpr float QSCALE = 0.18033688011112042f;  // log2(e)/8
constexpr int KVB = 128, NTILES = S_ / KVB;     // 16 kv tiles

__device__ __forceinline__ void gload16(const void* g, void* l) {
  __builtin_amdgcn_global_load_lds((const __attribute__((address_space(1))) void*)g,
                                   (__attribute__((address_space(3))) void*)l, 16, 0, 0);
}

// ---------------------------------------------------------------------------
// cast fp32 -> fp16, 8 elems/thread
// ---------------------------------------------------------------------------
__global__ __launch_bounds__(256) void cast_f32_f16(const float* __restrict__ in,
                                                    _Float16* __restrict__ out, int n8) {
  int i = blockIdx.x * 256 + threadIdx.x;
  if (i >= n8) return;
  float4 a = reinterpret_cast<const float4*>(in)[2 * i];
  float4 b = reinterpret_cast<const float4*>(in)[2 * i + 1];
  half8 h;
  h[0] = (_Float16)a.x; h[1] = (_Float16)a.y; h[2] = (_Float16)a.z; h[3] = (_Float16)a.w;
  h[4] = (_Float16)b.x; h[5] = (_Float16)b.y; h[6] = (_Float16)b.z; h[7] = (_Float16)b.w;
  reinterpret_cast<half8*>(out)[i] = h;
}

// ---------------------------------------------------------------------------
// W[K][N] fp32 -> WT[N][K] fp16 (64x64 tiles)
// ---------------------------------------------------------------------------
__global__ __launch_bounds__(256) void transpose_cast(const float* __restrict__ W,
                                                      _Float16* __restrict__ WT,
                                                      int K, int N) {
  __shared__ float Ws[64][65];
  const int n0 = blockIdx.x * 64, k0 = blockIdx.y * 64;
  const int t = threadIdx.x;
#pragma unroll
  for (int i = 0; i < 4; i++) {
    int idx = t + 256 * i;
    int r = idx >> 4, c4 = idx & 15;
    float4 v = *reinterpret_cast<const float4*>(W + (size_t)(k0 + r) * N + n0 + c4 * 4);
    Ws[r][c4 * 4 + 0] = v.x; Ws[r][c4 * 4 + 1] = v.y;
    Ws[r][c4 * 4 + 2] = v.z; Ws[r][c4 * 4 + 3] = v.w;
  }
  __syncthreads();
#pragma unroll
  for (int i = 0; i < 2; i++) {
    int idx = t + 256 * i;
    int r = idx >> 3, ck = idx & 7;
    half8 h;
#pragma unroll
    for (int j = 0; j < 8; j++) h[j] = (_Float16)Ws[ck * 8 + j][r];
    *reinterpret_cast<half8*>(WT + (size_t)(n0 + r) * K + k0 + ck * 8) = h;
  }
}

// ---------------------------------------------------------------------------
// fp16 MFMA GEMM: C[M][N] = A[M][K] @ BT[N][K]^T + bias  (m97-class structure)
// ---------------------------------------------------------------------------
template <bool OUT_HALF>
__global__ __launch_bounds__(256) void gemm_mfma(const _Float16* __restrict__ A,
                                                 const _Float16* __restrict__ BT,
                                                 const float* __restrict__ bias,
                                                 void* __restrict__ Cout,
                                                 int M, int N, int K,
                                                 float scale_lo, int ncut) {
  __shared__ _Float16 As[128 * 64];
  __shared__ _Float16 Bs[128 * 64];
  const int t = threadIdx.x, w = t >> 6, lane = t & 63;
  const int m0 = blockIdx.y * 128, n0 = blockIdx.x * 128;
  const int wr = (w >> 1) * 64, wc = (w & 1) * 64;

  floatx4 acc[4][4] = {};

  for (int k0 = 0; k0 < K; k0 += 64) {
    __syncthreads();
#pragma unroll
    for (int i = 0; i < 4; i++) {
      int idx = t + 256 * i;
      int r = idx >> 3, c = idx & 7;
      int cs = c ^ (r & 7);
      gload16(A + (size_t)(m0 + r) * K + k0 + cs * 8, (char*)As + idx * 16);
      gload16(BT + (size_t)(n0 + r) * K + k0 + cs * 8, (char*)Bs + idx * 16);
    }
    __syncthreads();
#pragma unroll
    for (int ks = 0; ks < 2; ks++) {
      half8 af[4], bf[4];
#pragma unroll
      for (int r = 0; r < 4; r++) {
        int row = wr + r * 16 + (lane & 15);
        int ch = (ks * 4 + (lane >> 4)) ^ (row & 7);
        af[r] = *reinterpret_cast<const half8*>((const char*)As + row * 128 + ch * 16);
      }
#pragma unroll
      for (int c = 0; c < 4; c++) {
        int row = wc + c * 16 + (lane & 15);
        int ch = (ks * 4 + (lane >> 4)) ^ (row & 7);
        bf[c] = *reinterpret_cast<const half8*>((const char*)Bs + row * 128 + ch * 16);
      }
#pragma unroll
      for (int r = 0; r < 4; r++)
#pragma unroll
        for (int c = 0; c < 4; c++)
          acc[r][c] = __builtin_amdgcn_mfma_f32_16x16x32_f16(af[r], bf[c], acc[r][c], 0, 0, 0);
    }
  }

#pragma unroll
  for (int r = 0; r < 4; r++)
#pragma unroll
    for (int c = 0; c < 4; c++) {
      int col = n0 + wc + c * 16 + (lane & 15);
      float bv = bias[col];
      float sc = (col < ncut) ? scale_lo : 1.0f;
#pragma unroll
      for (int reg = 0; reg < 4; reg++) {
        int row = m0 + wr + r * 16 + (lane >> 4) * 4 + reg;
        float v = (acc[r][c][reg] + bv) * sc;
        if (OUT_HALF)
          reinterpret_cast<_Float16*>(Cout)[(size_t)row * N + col] = (_Float16)v;
        else
          reinterpret_cast<float*>(Cout)[(size_t)row * N + col] = v;
      }
    }
}

// ---------------------------------------------------------------------------
// V transpose: qkv[B*S][3D] fp16 (V slice) -> Vt[(b*H+h)*64 + d][S] fp16
// ---------------------------------------------------------------------------
__global__ __launch_bounds__(256) void v_transpose(const _Float16* __restrict__ qkv,
                                                   _Float16* __restrict__ Vt) {
  __shared__ _Float16 Vs[64][72];
  const int s0 = blockIdx.x * 64, bh = blockIdx.y;
  const int b = bh >> 4, h = bh & 15;
  const int t = threadIdx.x;
#pragma unroll
  for (int i = 0; i < 2; i++) {
    int idx = t + 256 * i;
    int r = idx >> 3, c = idx & 7;
    half8 v = *reinterpret_cast<const half8*>(
        qkv + (size_t)(b * S_ + s0 + r) * (3 * D_) + 2 * D_ + h * 64 + c * 8);
    *reinterpret_cast<half8*>(&Vs[r][c * 8]) = v;
  }
  __syncthreads();
#pragma unroll
  for (int i = 0; i < 2; i++) {
    int idx = t + 256 * i;
    int d = idx >> 3, c = idx & 7;
    half8 o;
#pragma unroll
    for (int j = 0; j < 8; j++) o[j] = Vs[c * 8 + j][d];
    *reinterpret_cast<half8*>(Vt + ((size_t)bh * 64 + d) * S_ + s0 + c * 8) = o;
  }
}

// ---------------------------------------------------------------------------
// Flash attention, fp16 MFMA 32x32x16, KVB=128, double-buffered staging.
// 4 waves x 32 q-rows. Swapped QK^T and PV; q = lane&31 lane-local throughout.
// P never touches LDS: cvt_pkrtz + v_permlane32_swap_b32 builds the PV
// B-fragment in registers (T12). Defer-max (T13, THR=8 in exp2 domain).
// Staging: counted s_waitcnt vmcnt(8) -> next tile's 8 loads stay in flight.
// ---------------------------------------------------------------------------
__global__ __launch_bounds__(256) void flash_mfma(const _Float16* __restrict__ qkv,
                                                  const _Float16* __restrict__ Vt,
                                                  _Float16* __restrict__ attn_out) {
  const int qt = blockIdx.x, h = blockIdx.y, b = blockIdx.z;
  const int t = threadIdx.x, w = t >> 6, lane = t & 63;
  const int lo = lane & 31, hi = lane >> 5;

  __shared__ _Float16 Ks[2][KVB * 64];    // [kk][d] rows 128B, chunk^(r&7)
  __shared__ _Float16 Vts[2][64 * KVB];   // [d][kk] rows 256B, chunk^(r&15)

  // Q fragments (B operand; col=q=lo, k=d)
  const int qrow = qt * 128 + w * 32 + lo;
  const _Float16* qbase = qkv + (size_t)(b * S_ + qrow) * (3 * D_) + h * 64;
  half8 qf[4];
#pragma unroll
  for (int kd = 0; kd < 4; kd++)
    qf[kd] = *reinterpret_cast<const half8*>(qbase + kd * 16 + hi * 8);
  // Force Q loads to drain BEFORE pipelined staging starts (keeps the
  // in-loop vmcnt budget exact).
  asm volatile("" : "+v"(qf[0]), "+v"(qf[1]), "+v"(qf[2]), "+v"(qf[3]));

  const size_t kbase = (size_t)(b * S_) * (3 * D_) + D_ + h * 64;
  const size_t vbase = (size_t)(b * H_ + h) * 64 * S_;

  auto stage = [&](int buf, int tile) {
    const int kv0 = tile * KVB;
    const _Float16* kg = qkv + kbase + (size_t)kv0 * (3 * D_);
#pragma unroll
    for (int p = 0; p < 4; p++) {
      int idx = t + 256 * p;
      int r = idx >> 3, c = idx & 7, cs = c ^ (r & 7);
      gload16(kg + (size_t)r * (3 * D_) + cs * 8, (char*)&Ks[buf][0] + idx * 16);
    }
    const _Float16* vg = Vt + vbase + kv0;
#pragma unroll
    for (int p = 0; p < 4; p++) {
      int idx = t + 256 * p;
      int r = idx >> 4, c = idx & 15, cs = c ^ (r & 15);
      gload16(vg + (size_t)r * S_ + cs * 8, (char*)&Vts[buf][0] + idx * 16);
    }
  };

  floatx16 o0, o1;
#pragma unroll
  for (int r = 0; r < 16; r++) { o0[r] = 0.f; o1[r] = 0.f; }
  float m = -1e30f, l = 0.f;

  stage(0, 0);

  for (int tt = 0; tt < NTILES; ++tt) {
    const int cb = tt & 1;
    stage(cb ^ 1, (tt + 1) & (NTILES - 1));   // wrap: last iter re-stages tile 0 (unused)
    asm volatile("s_waitcnt vmcnt(8)" ::: "memory");
    __builtin_amdgcn_s_barrier();
    __builtin_amdgcn_sched_barrier(0);

    // ---- S^T = K @ Q^T : lane holds q=lo; kv = 32*sb + (reg&3)+8*(reg>>2)+4*hi
    const char* kb2 = (const char*)&Ks[cb][0];
    floatx16 s[4];
#pragma unroll
    for (int sb = 0; sb < 4; sb++)
#pragma unroll
      for (int r = 0; r < 16; r++) s[sb][r] = 0.f;
#pragma unroll
    for (int kd = 0; kd < 4; kd++) {
#pragma unroll
      for (int sb = 0; sb < 4; sb++) {
        int rr = sb * 32 + lo;
        half8 kf = *reinterpret_cast<const half8*>(
            kb2 + rr * 128 + (((kd * 2 + hi) ^ (rr & 7)) * 16));
        s[sb] = __builtin_amdgcn_mfma_f32_32x32x16_f16(kf, qf[kd], s[sb], 0, 0, 0);
      }
    }

    // ---- online softmax (exp2 domain), defer-max THR=8
    float pm = -1e30f;
#pragma unroll
    for (int sb = 0; sb < 4; sb++)
#pragma unroll
      for (int r = 0; r < 16; r++) pm = fmaxf(pm, s[sb][r]);
    pm = fmaxf(pm, __shfl_xor(pm, 32));
    if (!__all(pm <= m + 8.0f)) {
      float mn = fmaxf(m, pm);
      float al = __builtin_amdgcn_exp2f(m - mn);
      m = mn; l *= al;
#pragma unroll
      for (int r = 0; r < 16; r++) { o0[r] *= al; o1[r] *= al; }
    }
    float rs = 0.f;
#pragma unroll
    for (int sb = 0; sb < 4; sb++)
#pragma unroll
      for (int r = 0; r < 16; r++) {
        s[sb][r] = __builtin_amdgcn_exp2f(s[sb][r] - m);
        rs += s[sb][r];
      }
    rs += __shfl_xor(rs, 32);
    l += rs;

    // ---- O^T += V^T @ P^T ; P B-frag built in registers (cvt_pk + permlane)
    const char* vb2 = (const char*)&Vts[cb][0];
#pragma unroll
    for (int sb = 0; sb < 4; sb++) {
#pragma unroll
      for (int hf = 0; hf < 2; hf++) {
        const int rb = hf * 8;
        unsigned w0a = __builtin_bit_cast(unsigned, __builtin_amdgcn_cvt_pkrtz(s[sb][rb + 0], s[sb][rb + 1]));
        unsigned w0b = __builtin_bit_cast(unsigned, __builtin_amdgcn_cvt_pkrtz(s[sb][rb + 4], s[sb][rb + 5]));
        unsigned w1a = __builtin_bit_cast(unsigned, __builtin_amdgcn_cvt_pkrtz(s[sb][rb + 2], s[sb][rb + 3]));
        unsigned w1b = __builtin_bit_cast(unsigned, __builtin_amdgcn_cvt_pkrtz(s[sb][rb + 6], s[sb][rb + 7]));
        asm("v_permlane32_swap_b32 %0, %1" : "+v"(w0a), "+v"(w0b));
        asm("v_permlane32_swap_b32 %0, %1" : "+v"(w1a), "+v"(w1b));
        uint4v u; u[0] = w0a; u[1] = w1a; u[2] = w0b; u[3] = w1b;
        half8 pf = __builtin_bit_cast(half8, u);
        const int ks = sb * 2 + hf;        // k-step over kv, 0..7
        const int ch = ks * 2 + hi;
        half8 vf0 = *reinterpret_cast<const half8*>(vb2 + lo * 256 + ((ch ^ (lo & 15)) * 16));
        half8 vf1 = *reinterpret_cast<const half8*>(vb2 + (lo + 32) * 256 + ((ch ^ (lo & 15)) * 16));
        o0 = __builtin_amdgcn_mfma_f32_32x32x16_f16(vf0, pf, o0, 0, 0, 0);
        o1 = __builtin_amdgcn_mfma_f32_32x32x16_f16(vf1, pf, o1, 0, 0, 0);
      }
    }

    __builtin_amdgcn_sched_barrier(0);
    __builtin_amdgcn_s_barrier();
  }

  // epilogue: lane holds O^T[d][q=lo]; d = 32*mt + 8*rq + 4*hi + e
  float inv = 1.0f / l;
  _Float16* ob = attn_out + (size_t)(b * S_ + qrow) * D_ + h * 64;
#pragma unroll
  for (int mt = 0; mt < 2; mt++)
#pragma unroll
    for (int rq = 0; rq < 4; rq++) {
      half4 v;
#pragma unroll
      for (int e = 0; e < 4; e++) v[e] = (_Float16)(((mt ? o1 : o0)[4 * rq + e]) * inv);
      *reinterpret_cast<half4*>(ob + 32 * mt + 8 * rq + 4 * hi) = v;
    }
}

// ---------------------------------------------------------------------------
extern "C" void kernel_launch(void* const* d_in, const int* in_sizes, int n_in,
                              void* d_out, int out_size, void* d_ws, size_t ws_size,
                              hipStream_t stream) {
  const float* x     = (const float*)d_in[0];
  const float* W_qkv = (const float*)d_in[1];
  const float* b_qkv = (const float*)d_in[2];
  const float* W_out = (const float*)d_in[3];
  const float* b_out = (const float*)d_in[4];
  float* out = (float*)d_out;

  _Float16* xh   = (_Float16*)d_ws;                  // 4M halves  (8 MB)
  _Float16* WqT  = xh   + (size_t)M_ * D_;           // 3M         (6 MB)
  _Float16* WoT  = WqT  + (size_t)3 * D_ * D_;       // 1M         (2 MB)
  _Float16* qkvh = WoT  + (size_t)D_ * D_;           // 12M        (24 MB)
  _Float16* Vth  = qkvh + (size_t)M_ * 3 * D_;       // 4M         (8 MB)
  _Float16* atth = Vth  + (size_t)B_ * H_ * 64 * S_; // 4M         (8 MB)

  cast_f32_f16<<<(M_ * D_ / 8 + 255) / 256, 256, 0, stream>>>(x, xh, M_ * D_ / 8);
  transpose_cast<<<dim3(3 * D_ / 64, D_ / 64), 256, 0, stream>>>(W_qkv, WqT, D_, 3 * D_);
  transpose_cast<<<dim3(D_ / 64, D_ / 64), 256, 0, stream>>>(W_out, WoT, D_, D_);

  gemm_mfma<true><<<dim3(3 * D_ / 128, M_ / 128), 256, 0, stream>>>(
      xh, WqT, b_qkv, qkvh, M_, 3 * D_, D_, QSCALE, D_);

  v_transpose<<<dim3(S_ / 64, B_ * H_), 256, 0, stream>>>(qkvh, Vth);

  flash_mfma<<<dim3(S_ / 128, H_, B_), 256, 0, stream>>>(qkvh, Vth, atth);

  gemm_mfma<false><<<dim3(D_ / 128, M_ / 128), 256, 0, stream>>>(
      atth, WoT, b_out, out, M_, D_, D_, 1.0f, 0);
}

// Round 4
// 153.105 us; speedup vs baseline: 1.0108x; 1.0108x over previous
//
#include <hip/hip_runtime.h>

typedef _Float16 half8  __attribute__((ext_vector_type(8)));
typedef _Float16 half4  __attribute__((ext_vector_type(4)));
typedef float    floatx4  __attribute__((ext_vector_type(4)));
typedef float    floatx16 __attribute__((ext_vector_type(16)));
typedef unsigned int uint4v __attribute__((ext_vector_type(4)));

constexpr int B_ = 2, S_ = 2048, D_ = 1024, H_ = 16, M_ = 4096;
constexpr int NR_ = B_ * H_ * S_;               // 65536 (b,h,s) rows
constexpr float QSCALE = 0.18033688011112042f;  // log2(e)/8
constexpr int KVB = 64;                         // kv tile
constexpr int HT = 16;                          // tiles per half (1024/64)

__device__ __forceinline__ void gload16(const void* g, void* l) {
  __builtin_amdgcn_global_load_lds((const __attribute__((address_space(1))) void*)g,
                                   (__attribute__((address_space(3))) void*)l, 16, 0, 0);
}

// ---------------------------------------------------------------------------
// cast fp32 -> fp16, 8 elems/thread
// ---------------------------------------------------------------------------
__global__ __launch_bounds__(256) void cast_f32_f16(const float* __restrict__ in,
                                                    _Float16* __restrict__ out, int n8) {
  int i = blockIdx.x * 256 + threadIdx.x;
  if (i >= n8) return;
  float4 a = reinterpret_cast<const float4*>(in)[2 * i];
  float4 b = reinterpret_cast<const float4*>(in)[2 * i + 1];
  half8 h;
  h[0] = (_Float16)a.x; h[1] = (_Float16)a.y; h[2] = (_Float16)a.z; h[3] = (_Float16)a.w;
  h[4] = (_Float16)b.x; h[5] = (_Float16)b.y; h[6] = (_Float16)b.z; h[7] = (_Float16)b.w;
  reinterpret_cast<half8*>(out)[i] = h;
}

// ---------------------------------------------------------------------------
// W[K][N] fp32 -> WT[N][K] fp16 (64x64 tiles)
// ---------------------------------------------------------------------------
__global__ __launch_bounds__(256) void transpose_cast(const float* __restrict__ W,
                                                      _Float16* __restrict__ WT,
                                                      int K, int N) {
  __shared__ float Ws[64][65];
  const int n0 = blockIdx.x * 64, k0 = blockIdx.y * 64;
  const int t = threadIdx.x;
#pragma unroll
  for (int i = 0; i < 4; i++) {
    int idx = t + 256 * i;
    int r = idx >> 4, c4 = idx & 15;
    float4 v = *reinterpret_cast<const float4*>(W + (size_t)(k0 + r) * N + n0 + c4 * 4);
    Ws[r][c4 * 4 + 0] = v.x; Ws[r][c4 * 4 + 1] = v.y;
    Ws[r][c4 * 4 + 2] = v.z; Ws[r][c4 * 4 + 3] = v.w;
  }
  __syncthreads();
#pragma unroll
  for (int i = 0; i < 2; i++) {
    int idx = t + 256 * i;
    int r = idx >> 3, ck = idx & 7;
    half8 h;
#pragma unroll
    for (int j = 0; j < 8; j++) h[j] = (_Float16)Ws[ck * 8 + j][r];
    *reinterpret_cast<half8*>(WT + (size_t)(n0 + r) * K + k0 + ck * 8) = h;
  }
}

// ---------------------------------------------------------------------------
// fp16 MFMA GEMM: C[M][N] = A[M][K] @ BT[N][K]^T + bias  (m97-class structure)
// ---------------------------------------------------------------------------
template <bool OUT_HALF>
__global__ __launch_bounds__(256) void gemm_mfma(const _Float16* __restrict__ A,
                                                 const _Float16* __restrict__ BT,
                                                 const float* __restrict__ bias,
                                                 void* __restrict__ Cout,
                                                 int M, int N, int K,
                                                 float scale_lo, int ncut) {
  __shared__ _Float16 As[128 * 64];
  __shared__ _Float16 Bs[128 * 64];
  const int t = threadIdx.x, w = t >> 6, lane = t & 63;
  const int m0 = blockIdx.y * 128, n0 = blockIdx.x * 128;
  const int wr = (w >> 1) * 64, wc = (w & 1) * 64;

  floatx4 acc[4][4] = {};

  for (int k0 = 0; k0 < K; k0 += 64) {
    __syncthreads();
#pragma unroll
    for (int i = 0; i < 4; i++) {
      int idx = t + 256 * i;
      int r = idx >> 3, c = idx & 7;
      int cs = c ^ (r & 7);
      gload16(A + (size_t)(m0 + r) * K + k0 + cs * 8, (char*)As + idx * 16);
      gload16(BT + (size_t)(n0 + r) * K + k0 + cs * 8, (char*)Bs + idx * 16);
    }
    __syncthreads();
#pragma unroll
    for (int ks = 0; ks < 2; ks++) {
      half8 af[4], bf[4];
#pragma unroll
      for (int r = 0; r < 4; r++) {
        int row = wr + r * 16 + (lane & 15);
        int ch = (ks * 4 + (lane >> 4)) ^ (row & 7);
        af[r] = *reinterpret_cast<const half8*>((const char*)As + row * 128 + ch * 16);
      }
#pragma unroll
      for (int c = 0; c < 4; c++) {
        int row = wc + c * 16 + (lane & 15);
        int ch = (ks * 4 + (lane >> 4)) ^ (row & 7);
        bf[c] = *reinterpret_cast<const half8*>((const char*)Bs + row * 128 + ch * 16);
      }
#pragma unroll
      for (int r = 0; r < 4; r++)
#pragma unroll
        for (int c = 0; c < 4; c++)
          acc[r][c] = __builtin_amdgcn_mfma_f32_16x16x32_f16(af[r], bf[c], acc[r][c], 0, 0, 0);
    }
  }

#pragma unroll
  for (int r = 0; r < 4; r++)
#pragma unroll
    for (int c = 0; c < 4; c++) {
      int col = n0 + wc + c * 16 + (lane & 15);
      float bv = bias[col];
      float sc = (col < ncut) ? scale_lo : 1.0f;
#pragma unroll
      for (int reg = 0; reg < 4; reg++) {
        int row = m0 + wr + r * 16 + (lane >> 4) * 4 + reg;
        float v = (acc[r][c][reg] + bv) * sc;
        if (OUT_HALF)
          reinterpret_cast<_Float16*>(Cout)[(size_t)row * N + col] = (_Float16)v;
        else
          reinterpret_cast<float*>(Cout)[(size_t)row * N + col] = v;
      }
    }
}

// ---------------------------------------------------------------------------
// V transpose: qkv[B*S][3D] fp16 (V slice) -> Vt[(b*H+h)*64 + d][S] fp16
// ---------------------------------------------------------------------------
__global__ __launch_bounds__(256) void v_transpose(const _Float16* __restrict__ qkv,
                                                   _Float16* __restrict__ Vt) {
  __shared__ _Float16 Vs[64][72];
  const int s0 = blockIdx.x * 64, bh = blockIdx.y;
  const int b = bh >> 4, h = bh & 15;
  const int t = threadIdx.x;
#pragma unroll
  for (int i = 0; i < 2; i++) {
    int idx = t + 256 * i;
    int r = idx >> 3, c = idx & 7;
    half8 v = *reinterpret_cast<const half8*>(
        qkv + (size_t)(b * S_ + s0 + r) * (3 * D_) + 2 * D_ + h * 64 + c * 8);
    *reinterpret_cast<half8*>(&Vs[r][c * 8]) = v;
  }
  __syncthreads();
#pragma unroll
  for (int i = 0; i < 2; i++) {
    int idx = t + 256 * i;
    int d = idx >> 3, c = idx & 7;
    half8 o;
#pragma unroll
    for (int j = 0; j < 8; j++) o[j] = Vs[c * 8 + j][d];
    *reinterpret_cast<half8*>(Vt + ((size_t)bh * 64 + d) * S_ + s0 + c * 8) = o;
  }
}

// ---------------------------------------------------------------------------
// Flash attention, fp16 MFMA 32x32x16, KVB=64 double-buffered, KV-SPLIT x2.
// Grid (S/128, H, B*2): z = b*2 + split; block = 4 waves x 32 q-rows.
// LDS 32 KiB -> 4 blocks/CU with grid 1024 -> ~16 waves/CU (occupancy fix).
// Swapped QK^T / PV; P in registers via cvt_pkrtz + permlane32_swap (T12);
// defer-max (T13); counted vmcnt(4) staging (T4); setprio on MFMA (T5).
// Output: normalized fp16 partial O + key = m + log2(l) per row.
// ---------------------------------------------------------------------------
__global__ __launch_bounds__(256) void flash_mfma(const _Float16* __restrict__ qkv,
                                                  const _Float16* __restrict__ Vt,
                                                  _Float16* __restrict__ Opart,
                                                  float* __restrict__ keys) {
  const int qt = blockIdx.x, h = blockIdx.y;
  const int b = blockIdx.z >> 1, sp = blockIdx.z & 1;
  const int t = threadIdx.x, w = t >> 6, lane = t & 63;
  const int lo = lane & 31, hi = lane >> 5;

  __shared__ _Float16 Ks[2][KVB * 64];    // [kk][d] rows 128B, chunk^(r&7)
  __shared__ _Float16 Vts[2][64 * KVB];   // [d][kk] rows 128B, chunk^(r&7)

  // Q fragments (B operand; col=q=lo, k=d)
  const int qrow = qt * 128 + w * 32 + lo;
  const _Float16* qbase = qkv + (size_t)(b * S_ + qrow) * (3 * D_) + h * 64;
  half8 qf[4];
#pragma unroll
  for (int kd = 0; kd < 4; kd++)
    qf[kd] = *reinterpret_cast<const half8*>(qbase + kd * 16 + hi * 8);
  asm volatile("" : "+v"(qf[0]), "+v"(qf[1]), "+v"(qf[2]), "+v"(qf[3]));

  const size_t kbase = (size_t)(b * S_) * (3 * D_) + D_ + h * 64;
  const size_t vbase = (size_t)(b * H_ + h) * 64 * S_;
  const int kvbase = sp * (S_ / 2);

  auto stage = [&](int buf, int tile) {
    const int kv0 = kvbase + tile * KVB;
    const _Float16* kg = qkv + kbase + (size_t)kv0 * (3 * D_);
#pragma unroll
    for (int p = 0; p < 2; p++) {
      int idx = t + 256 * p;
      int r = idx >> 3, c = idx & 7, cs = c ^ (r & 7);
      gload16(kg + (size_t)r * (3 * D_) + cs * 8, (char*)&Ks[buf][0] + idx * 16);
    }
    const _Float16* vg = Vt + vbase + kv0;
#pragma unroll
    for (int p = 0; p < 2; p++) {
      int idx = t + 256 * p;
      int r = idx >> 3, c = idx & 7, cs = c ^ (r & 7);
      gload16(vg + (size_t)r * S_ + cs * 8, (char*)&Vts[buf][0] + idx * 16);
    }
  };

  floatx16 o0, o1;
#pragma unroll
  for (int r = 0; r < 16; r++) { o0[r] = 0.f; o1[r] = 0.f; }
  float m = -1e30f, l = 0.f;

  stage(0, 0);

  for (int tt = 0; tt < HT; ++tt) {
    const int cb = tt & 1;
    stage(cb ^ 1, (tt + 1) & (HT - 1));   // wrap: last iter re-stages tile 0 (unused)
    asm volatile("s_waitcnt vmcnt(4)" ::: "memory");
    __builtin_amdgcn_s_barrier();
    __builtin_amdgcn_sched_barrier(0);

    // ---- S^T = K @ Q^T : lane holds q=lo; kv = 32*sb + (reg&3)+8*(reg>>2)+4*hi
    const char* kb2 = (const char*)&Ks[cb][0];
    floatx16 s[2];
#pragma unroll
    for (int sb = 0; sb < 2; sb++)
#pragma unroll
      for (int r = 0; r < 16; r++) s[sb][r] = 0.f;
    __builtin_amdgcn_s_setprio(1);
#pragma unroll
    for (int kd = 0; kd < 4; kd++) {
#pragma unroll
      for (int sb = 0; sb < 2; sb++) {
        int rr = sb * 32 + lo;
        half8 kf = *reinterpret_cast<const half8*>(
            kb2 + rr * 128 + (((kd * 2 + hi) ^ (rr & 7)) * 16));
        s[sb] = __builtin_amdgcn_mfma_f32_32x32x16_f16(kf, qf[kd], s[sb], 0, 0, 0);
      }
    }
    __builtin_amdgcn_s_setprio(0);

    // ---- online softmax (exp2 domain), defer-max THR=8
    float pm = -1e30f;
#pragma unroll
    for (int sb = 0; sb < 2; sb++)
#pragma unroll
      for (int r = 0; r < 16; r++) pm = fmaxf(pm, s[sb][r]);
    pm = fmaxf(pm, __shfl_xor(pm, 32));
    if (!__all(pm <= m + 8.0f)) {
      float mn = fmaxf(m, pm);
      float al = __builtin_amdgcn_exp2f(m - mn);
      m = mn; l *= al;
#pragma unroll
      for (int r = 0; r < 16; r++) { o0[r] *= al; o1[r] *= al; }
    }
    float rs = 0.f;
#pragma unroll
    for (int sb = 0; sb < 2; sb++)
#pragma unroll
      for (int r = 0; r < 16; r++) {
        s[sb][r] = __builtin_amdgcn_exp2f(s[sb][r] - m);
        rs += s[sb][r];
      }
    rs += __shfl_xor(rs, 32);
    l += rs;

    // ---- O^T += V^T @ P^T ; P B-frag built in registers (cvt_pk + permlane)
    const char* vb2 = (const char*)&Vts[cb][0];
    __builtin_amdgcn_s_setprio(1);
#pragma unroll
    for (int sb = 0; sb < 2; sb++) {
#pragma unroll
      for (int hf = 0; hf < 2; hf++) {
        const int rb = hf * 8;
        unsigned w0a = __builtin_bit_cast(unsigned, __builtin_amdgcn_cvt_pkrtz(s[sb][rb + 0], s[sb][rb + 1]));
        unsigned w0b = __builtin_bit_cast(unsigned, __builtin_amdgcn_cvt_pkrtz(s[sb][rb + 4], s[sb][rb + 5]));
        unsigned w1a = __builtin_bit_cast(unsigned, __builtin_amdgcn_cvt_pkrtz(s[sb][rb + 2], s[sb][rb + 3]));
        unsigned w1b = __builtin_bit_cast(unsigned, __builtin_amdgcn_cvt_pkrtz(s[sb][rb + 6], s[sb][rb + 7]));
        asm("v_permlane32_swap_b32 %0, %1" : "+v"(w0a), "+v"(w0b));
        asm("v_permlane32_swap_b32 %0, %1" : "+v"(w1a), "+v"(w1b));
        uint4v u; u[0] = w0a; u[1] = w1a; u[2] = w0b; u[3] = w1b;
        half8 pf = __builtin_bit_cast(half8, u);
        const int ks = sb * 2 + hf;        // k-step over kv, 0..3
        const int ch = ks * 2 + hi;
        half8 vf0 = *reinterpret_cast<const half8*>(vb2 + lo * 128 + ((ch ^ (lo & 7)) * 16));
        half8 vf1 = *reinterpret_cast<const half8*>(vb2 + (lo + 32) * 128 + ((ch ^ (lo & 7)) * 16));
        o0 = __builtin_amdgcn_mfma_f32_32x32x16_f16(vf0, pf, o0, 0, 0, 0);
        o1 = __builtin_amdgcn_mfma_f32_32x32x16_f16(vf1, pf, o1, 0, 0, 0);
      }
    }
    __builtin_amdgcn_s_setprio(0);

    __builtin_amdgcn_sched_barrier(0);
    __builtin_amdgcn_s_barrier();
  }

  // epilogue: normalized partial O (fp16) + key = m + log2(l)
  float inv = 1.0f / l;
  const int gr = (b * H_ + h) * S_ + qrow;
  _Float16* ob = Opart + ((size_t)sp * NR_ + gr) * 64;
#pragma unroll
  for (int mt = 0; mt < 2; mt++)
#pragma unroll
    for (int rq = 0; rq < 4; rq++) {
      half4 v;
#pragma unroll
      for (int e = 0; e < 4; e++) v[e] = (_Float16)(((mt ? o1 : o0)[4 * rq + e]) * inv);
      *reinterpret_cast<half4*>(ob + 32 * mt + 8 * rq + 4 * hi) = v;
    }
  if (hi == 0) keys[sp * NR_ + gr] = m + __log2f(l);
}

// ---------------------------------------------------------------------------
// Combine the two KV-split halves: out = (w0*O0 + w1*O1)/(w0+w1), wi = 2^keyi
// ---------------------------------------------------------------------------
__global__ __launch_bounds__(256) void flash_combine(const _Float16* __restrict__ Opart,
                                                     const float* __restrict__ keys,
                                                     _Float16* __restrict__ attn_out) {
  const int gr = blockIdx.x * 256 + threadIdx.x;
  const float k0 = keys[gr], k1 = keys[NR_ + gr];
  const float mx = fmaxf(k0, k1);
  const float w0 = __builtin_amdgcn_exp2f(k0 - mx);
  const float w1 = __builtin_amdgcn_exp2f(k1 - mx);
  const float inv = 1.0f / (w0 + w1);
  const float a0 = w0 * inv, a1 = w1 * inv;
  const int bh = gr >> 11, qs = gr & 2047, b = bh >> 4, h = bh & 15;
  const half8* p0 = reinterpret_cast<const half8*>(Opart + (size_t)gr * 64);
  const half8* p1 = reinterpret_cast<const half8*>(Opart + ((size_t)NR_ + gr) * 64);
  half8* ob = reinterpret_cast<half8*>(
      attn_out + ((size_t)(b * S_ + qs)) * D_ + h * 64);
#pragma unroll
  for (int j = 0; j < 8; j++) {
    half8 x0 = p0[j], x1 = p1[j];
    half8 o;
#pragma unroll
    for (int e = 0; e < 8; e++)
      o[e] = (_Float16)(a0 * (float)x0[e] + a1 * (float)x1[e]);
    ob[j] = o;
  }
}

// ---------------------------------------------------------------------------
extern "C" void kernel_launch(void* const* d_in, const int* in_sizes, int n_in,
                              void* d_out, int out_size, void* d_ws, size_t ws_size,
                              hipStream_t stream) {
  const float* x     = (const float*)d_in[0];
  const float* W_qkv = (const float*)d_in[1];
  const float* b_qkv = (const float*)d_in[2];
  const float* W_out = (const float*)d_in[3];
  const float* b_out = (const float*)d_in[4];
  float* out = (float*)d_out;

  // Workspace packing (58.5 MB, aliased; ws >= 64 MB proven in R1):
  //   xh [8MB] (dead after GEMM1; atth aliases it)
  //   qkvh [24MB] | Vth [8MB] | WoT [2MB]
  //   WqT [6MB] (dead after GEMM1; Opart[16MB]+keys[0.5MB] alias it)
  _Float16* xh    = (_Float16*)d_ws;
  _Float16* qkvh  = xh + (size_t)M_ * D_;
  _Float16* Vth   = qkvh + (size_t)M_ * 3 * D_;
  _Float16* WoT   = Vth + (size_t)B_ * H_ * 64 * S_;
  _Float16* WqT   = WoT + (size_t)D_ * D_;
  _Float16* Opart = WqT;                                  // alias (WqT dead by flash)
  float*    keys  = (float*)(Opart + (size_t)2 * NR_ * 64);
  _Float16* atth  = xh;                                   // alias (xh dead by combine)

  cast_f32_f16<<<(M_ * D_ / 8 + 255) / 256, 256, 0, stream>>>(x, xh, M_ * D_ / 8);
  transpose_cast<<<dim3(3 * D_ / 64, D_ / 64), 256, 0, stream>>>(W_qkv, WqT, D_, 3 * D_);
  transpose_cast<<<dim3(D_ / 64, D_ / 64), 256, 0, stream>>>(W_out, WoT, D_, D_);

  gemm_mfma<true><<<dim3(3 * D_ / 128, M_ / 128), 256, 0, stream>>>(
      xh, WqT, b_qkv, qkvh, M_, 3 * D_, D_, QSCALE, D_);

  v_transpose<<<dim3(S_ / 64, B_ * H_), 256, 0, stream>>>(qkvh, Vth);

  flash_mfma<<<dim3(S_ / 128, H_, B_ * 2), 256, 0, stream>>>(qkvh, Vth, Opart, keys);

  flash_combine<<<NR_ / 256, 256, 0, stream>>>(Opart, keys, atth);

  gemm_mfma<false><<<dim3(D_ / 128, M_ / 128), 256, 0, stream>>>(
      atth, WoT, b_out, out, M_, D_, D_, 1.0f, 0);
}

// Round 6
// 149.391 us; speedup vs baseline: 1.0359x; 1.0249x over previous
//
#include <hip/hip_runtime.h>

typedef _Float16 half8  __attribute__((ext_vector_type(8)));
typedef _Float16 half4  __attribute__((ext_vector_type(4)));
typedef float    floatx4  __attribute__((ext_vector_type(4)));
typedef float    floatx16 __attribute__((ext_vector_type(16)));
typedef unsigned int uint4v __attribute__((ext_vector_type(4)));

constexpr int B_ = 2, S_ = 2048, D_ = 1024, H_ = 16, M_ = 4096;
constexpr int NR_ = B_ * H_ * S_;               // 65536 (b,h,s) rows
constexpr float QSCALE = 0.18033688011112042f;  // log2(e)/8
constexpr int KVB = 64;                         // kv tile
constexpr int HT = 16;                          // tiles per half (1024/64)

__device__ __forceinline__ void gload16(const void* g, void* l) {
  __builtin_amdgcn_global_load_lds((const __attribute__((address_space(1))) void*)g,
                                   (__attribute__((address_space(3))) void*)l, 16, 0, 0);
}

// ---------------------------------------------------------------------------
// cast fp32 -> fp16, 8 elems/thread
// ---------------------------------------------------------------------------
__global__ __launch_bounds__(256) void cast_f32_f16(const float* __restrict__ in,
                                                    _Float16* __restrict__ out, int n8) {
  int i = blockIdx.x * 256 + threadIdx.x;
  if (i >= n8) return;
  float4 a = reinterpret_cast<const float4*>(in)[2 * i];
  float4 b = reinterpret_cast<const float4*>(in)[2 * i + 1];
  half8 h;
  h[0] = (_Float16)a.x; h[1] = (_Float16)a.y; h[2] = (_Float16)a.z; h[3] = (_Float16)a.w;
  h[4] = (_Float16)b.x; h[5] = (_Float16)b.y; h[6] = (_Float16)b.z; h[7] = (_Float16)b.w;
  reinterpret_cast<half8*>(out)[i] = h;
}

// ---------------------------------------------------------------------------
// W[K][N] fp32 -> WT[N][K] fp16 (64x64 tiles)
// ---------------------------------------------------------------------------
__global__ __launch_bounds__(256) void transpose_cast(const float* __restrict__ W,
                                                      _Float16* __restrict__ WT,
                                                      int K, int N) {
  __shared__ float Ws[64][65];
  const int n0 = blockIdx.x * 64, k0 = blockIdx.y * 64;
  const int t = threadIdx.x;
#pragma unroll
  for (int i = 0; i < 4; i++) {
    int idx = t + 256 * i;
    int r = idx >> 4, c4 = idx & 15;
    float4 v = *reinterpret_cast<const float4*>(W + (size_t)(k0 + r) * N + n0 + c4 * 4);
    Ws[r][c4 * 4 + 0] = v.x; Ws[r][c4 * 4 + 1] = v.y;
    Ws[r][c4 * 4 + 2] = v.z; Ws[r][c4 * 4 + 3] = v.w;
  }
  __syncthreads();
#pragma unroll
  for (int i = 0; i < 2; i++) {
    int idx = t + 256 * i;
    int r = idx >> 3, ck = idx & 7;
    half8 h;
#pragma unroll
    for (int j = 0; j < 8; j++) h[j] = (_Float16)Ws[ck * 8 + j][r];
    *reinterpret_cast<half8*>(WT + (size_t)(n0 + r) * K + k0 + ck * 8) = h;
  }
}

// ---------------------------------------------------------------------------
// 8-phase 256x256 fp16 MFMA GEMM (T2+T3+T4+T5): C = A[M,K] @ BT[N,K]^T + bias
// 512 thr = 8 waves (2M x 4N); BK=64; 128 KiB LDS double-buffer (dynamic).
// Per K-tile: STAGE(next) -> vmcnt(8) -> s_barrier -> 4 phases of
// {12 ds_read_b128; setprio(1); 16 MFMA; setprio(0); sched_barrier; s_barrier}.
// Counted vmcnt: next tile's 8 loads stay in flight across all barriers.
// Grid: flat M/256 * N/256, bijective XCD swizzle (nwg % 8 == 0 required).
// NOTE: no arrays of LDS pointers (hipcc static-initializer bug) — bases are
// recomputed as smem + offset at each use.
// ---------------------------------------------------------------------------
__global__ __launch_bounds__(512, 2) void gemm256_mfma(
    const _Float16* __restrict__ A, const _Float16* __restrict__ BT,
    const float* __restrict__ bias, _Float16* __restrict__ Cout,
    int M, int N, int K, float scale_lo, int ncut) {
  extern __shared__ char smem[];   // 131072 B: As[2][32KB] | Bs[2][32KB]
  const int tid = threadIdx.x, w = tid >> 6, lane = tid & 63;
  const int wm = w >> 2, wn = w & 3;

  // XCD-aware bijective swizzle over flat grid
  const int nwg = gridDim.x, cpx = nwg >> 3;
  const int wg = (blockIdx.x & 7) * cpx + (blockIdx.x >> 3);
  const int nbx = N >> 8;
  const int bx = wg % nbx, by = wg / nbx;
  const int m0 = by * 256, n0 = bx * 256;

  const int NT = K >> 6;

  auto stage = [&](int buf, int kt) {
    const int k0 = kt * 64;
    char* Ad = smem + buf * 32768;
    char* Bd = smem + 65536 + buf * 32768;
#pragma unroll
    for (int i = 0; i < 4; i++) {
      int idx = tid + 512 * i;
      int r = idx >> 3, c = idx & 7, cs = c ^ (r & 7);
      gload16(A + (size_t)(m0 + r) * K + k0 + cs * 8, Ad + idx * 16);
    }
#pragma unroll
    for (int i = 0; i < 4; i++) {
      int idx = tid + 512 * i;
      int r = idx >> 3, c = idx & 7, cs = c ^ (r & 7);
      gload16(BT + (size_t)(n0 + r) * K + k0 + cs * 8, Bd + idx * 16);
    }
  };

  floatx4 acc[8][4] = {};

  stage(0, 0);

  for (int kt = 0; kt < NT; ++kt) {
    const int p = kt & 1;
    if (kt + 1 < NT) {
      stage(p ^ 1, kt + 1);                            // issue next tile first
      asm volatile("s_waitcnt vmcnt(8)" ::: "memory"); // this tile landed; next in flight
    } else {
      asm volatile("s_waitcnt vmcnt(0)" ::: "memory"); // last tile: drain
    }
    __builtin_amdgcn_s_barrier();

    const char* Ab = smem + p * 32768;
    const char* Bb = smem + 65536 + p * 32768;
#pragma unroll
    for (int q = 0; q < 4; q++) {
      half8 af[2][2], bf[4][2];
#pragma unroll
      for (int e = 0; e < 2; e++)
#pragma unroll
        for (int ks = 0; ks < 2; ks++) {
          int row = wm * 128 + (2 * q + e) * 16 + (lane & 15);
          int ch = (ks * 4 + (lane >> 4)) ^ (row & 7);
          af[e][ks] = *reinterpret_cast<const half8*>(Ab + row * 128 + ch * 16);
        }
#pragma unroll
      for (int n = 0; n < 4; n++)
#pragma unroll
        for (int ks = 0; ks < 2; ks++) {
          int row = wn * 64 + n * 16 + (lane & 15);
          int ch = (ks * 4 + (lane >> 4)) ^ (row & 7);
          bf[n][ks] = *reinterpret_cast<const half8*>(Bb + row * 128 + ch * 16);
        }
      __builtin_amdgcn_s_setprio(1);
#pragma unroll
      for (int ks = 0; ks < 2; ks++)
#pragma unroll
        for (int e = 0; e < 2; e++)
#pragma unroll
          for (int n = 0; n < 4; n++)
            acc[2 * q + e][n] = __builtin_amdgcn_mfma_f32_16x16x32_f16(
                af[e][ks], bf[n][ks], acc[2 * q + e][n], 0, 0, 0);
      __builtin_amdgcn_s_setprio(0);
      __builtin_amdgcn_sched_barrier(0);
      __builtin_amdgcn_s_barrier();
    }
  }

#pragma unroll
  for (int mf = 0; mf < 8; mf++)
#pragma unroll
    for (int n = 0; n < 4; n++) {
      int col = n0 + wn * 64 + n * 16 + (lane & 15);
      float bv = bias[col];
      float sc = (col < ncut) ? scale_lo : 1.0f;
#pragma unroll
      for (int reg = 0; reg < 4; reg++) {
        int row = m0 + wm * 128 + mf * 16 + (lane >> 4) * 4 + reg;
        Cout[(size_t)row * N + col] = (_Float16)((acc[mf][n][reg] + bv) * sc);
      }
    }
}

// ---------------------------------------------------------------------------
// fp16 MFMA GEMM, 128x128 tile (m97-class) — used for the output projection
// ---------------------------------------------------------------------------
template <bool OUT_HALF>
__global__ __launch_bounds__(256) void gemm_mfma(const _Float16* __restrict__ A,
                                                 const _Float16* __restrict__ BT,
                                                 const float* __restrict__ bias,
                                                 void* __restrict__ Cout,
                                                 int M, int N, int K,
                                                 float scale_lo, int ncut) {
  __shared__ _Float16 As[128 * 64];
  __shared__ _Float16 Bs[128 * 64];
  const int t = threadIdx.x, w = t >> 6, lane = t & 63;
  const int m0 = blockIdx.y * 128, n0 = blockIdx.x * 128;
  const int wr = (w >> 1) * 64, wc = (w & 1) * 64;

  floatx4 acc[4][4] = {};

  for (int k0 = 0; k0 < K; k0 += 64) {
    __syncthreads();
#pragma unroll
    for (int i = 0; i < 4; i++) {
      int idx = t + 256 * i;
      int r = idx >> 3, c = idx & 7;
      int cs = c ^ (r & 7);
      gload16(A + (size_t)(m0 + r) * K + k0 + cs * 8, (char*)As + idx * 16);
      gload16(BT + (size_t)(n0 + r) * K + k0 + cs * 8, (char*)Bs + idx * 16);
    }
    __syncthreads();
#pragma unroll
    for (int ks = 0; ks < 2; ks++) {
      half8 af[4], bf[4];
#pragma unroll
      for (int r = 0; r < 4; r++) {
        int row = wr + r * 16 + (lane & 15);
        int ch = (ks * 4 + (lane >> 4)) ^ (row & 7);
        af[r] = *reinterpret_cast<const half8*>((const char*)As + row * 128 + ch * 16);
      }
#pragma unroll
      for (int c = 0; c < 4; c++) {
        int row = wc + c * 16 + (lane & 15);
        int ch = (ks * 4 + (lane >> 4)) ^ (row & 7);
        bf[c] = *reinterpret_cast<const half8*>((const char*)Bs + row * 128 + ch * 16);
      }
#pragma unroll
      for (int r = 0; r < 4; r++)
#pragma unroll
        for (int c = 0; c < 4; c++)
          acc[r][c] = __builtin_amdgcn_mfma_f32_16x16x32_f16(af[r], bf[c], acc[r][c], 0, 0, 0);
    }
  }

#pragma unroll
  for (int r = 0; r < 4; r++)
#pragma unroll
    for (int c = 0; c < 4; c++) {
      int col = n0 + wc + c * 16 + (lane & 15);
      float bv = bias[col];
      float sc = (col < ncut) ? scale_lo : 1.0f;
#pragma unroll
      for (int reg = 0; reg < 4; reg++) {
        int row = m0 + wr + r * 16 + (lane >> 4) * 4 + reg;
        float v = (acc[r][c][reg] + bv) * sc;
        if (OUT_HALF)
          reinterpret_cast<_Float16*>(Cout)[(size_t)row * N + col] = (_Float16)v;
        else
          reinterpret_cast<float*>(Cout)[(size_t)row * N + col] = v;
      }
    }
}

// ---------------------------------------------------------------------------
// V transpose: qkv[B*S][3D] fp16 (V slice) -> Vt[(b*H+h)*64 + d][S] fp16
// ---------------------------------------------------------------------------
__global__ __launch_bounds__(256) void v_transpose(const _Float16* __restrict__ qkv,
                                                   _Float16* __restrict__ Vt) {
  __shared__ _Float16 Vs[64][72];
  const int s0 = blockIdx.x * 64, bh = blockIdx.y;
  const int b = bh >> 4, h = bh & 15;
  const int t = threadIdx.x;
#pragma unroll
  for (int i = 0; i < 2; i++) {
    int idx = t + 256 * i;
    int r = idx >> 3, c = idx & 7;
    half8 v = *reinterpret_cast<const half8*>(
        qkv + (size_t)(b * S_ + s0 + r) * (3 * D_) + 2 * D_ + h * 64 + c * 8);
    *reinterpret_cast<half8*>(&Vs[r][c * 8]) = v;
  }
  __syncthreads();
#pragma unroll
  for (int i = 0; i < 2; i++) {
    int idx = t + 256 * i;
    int d = idx >> 3, c = idx & 7;
    half8 o;
#pragma unroll
    for (int j = 0; j < 8; j++) o[j] = Vs[c * 8 + j][d];
    *reinterpret_cast<half8*>(Vt + ((size_t)bh * 64 + d) * S_ + s0 + c * 8) = o;
  }
}

// ---------------------------------------------------------------------------
// Flash attention, fp16 MFMA 32x32x16, KVB=64 double-buffered, KV-SPLIT x2.
// ---------------------------------------------------------------------------
__global__ __launch_bounds__(256) void flash_mfma(const _Float16* __restrict__ qkv,
                                                  const _Float16* __restrict__ Vt,
                                                  _Float16* __restrict__ Opart,
                                                  float* __restrict__ keys) {
  const int qt = blockIdx.x, h = blockIdx.y;
  const int b = blockIdx.z >> 1, sp = blockIdx.z & 1;
  const int t = threadIdx.x, w = t >> 6, lane = t & 63;
  const int lo = lane & 31, hi = lane >> 5;

  __shared__ _Float16 Ks[2][KVB * 64];    // [kk][d] rows 128B, chunk^(r&7)
  __shared__ _Float16 Vts[2][64 * KVB];   // [d][kk] rows 128B, chunk^(r&7)

  const int qrow = qt * 128 + w * 32 + lo;
  const _Float16* qbase = qkv + (size_t)(b * S_ + qrow) * (3 * D_) + h * 64;
  half8 qf[4];
#pragma unroll
  for (int kd = 0; kd < 4; kd++)
    qf[kd] = *reinterpret_cast<const half8*>(qbase + kd * 16 + hi * 8);
  asm volatile("" : "+v"(qf[0]), "+v"(qf[1]), "+v"(qf[2]), "+v"(qf[3]));

  const size_t kbase = (size_t)(b * S_) * (3 * D_) + D_ + h * 64;
  const size_t vbase = (size_t)(b * H_ + h) * 64 * S_;
  const int kvbase = sp * (S_ / 2);

  auto stage = [&](int buf, int tile) {
    const int kv0 = kvbase + tile * KVB;
    const _Float16* kg = qkv + kbase + (size_t)kv0 * (3 * D_);
#pragma unroll
    for (int p = 0; p < 2; p++) {
      int idx = t + 256 * p;
      int r = idx >> 3, c = idx & 7, cs = c ^ (r & 7);
      gload16(kg + (size_t)r * (3 * D_) + cs * 8, (char*)&Ks[buf][0] + idx * 16);
    }
    const _Float16* vg = Vt + vbase + kv0;
#pragma unroll
    for (int p = 0; p < 2; p++) {
      int idx = t + 256 * p;
      int r = idx >> 3, c = idx & 7, cs = c ^ (r & 7);
      gload16(vg + (size_t)r * S_ + cs * 8, (char*)&Vts[buf][0] + idx * 16);
    }
  };

  floatx16 o0, o1;
#pragma unroll
  for (int r = 0; r < 16; r++) { o0[r] = 0.f; o1[r] = 0.f; }
  float m = -1e30f, l = 0.f;

  stage(0, 0);

  for (int tt = 0; tt < HT; ++tt) {
    const int cb = tt & 1;
    stage(cb ^ 1, (tt + 1) & (HT - 1));
    asm volatile("s_waitcnt vmcnt(4)" ::: "memory");
    __builtin_amdgcn_s_barrier();
    __builtin_amdgcn_sched_barrier(0);

    const char* kb2 = (const char*)&Ks[cb][0];
    floatx16 s[2];
#pragma unroll
    for (int sb = 0; sb < 2; sb++)
#pragma unroll
      for (int r = 0; r < 16; r++) s[sb][r] = 0.f;
    __builtin_amdgcn_s_setprio(1);
#pragma unroll
    for (int kd = 0; kd < 4; kd++) {
#pragma unroll
      for (int sb = 0; sb < 2; sb++) {
        int rr = sb * 32 + lo;
        half8 kf = *reinterpret_cast<const half8*>(
            kb2 + rr * 128 + (((kd * 2 + hi) ^ (rr & 7)) * 16));
        s[sb] = __builtin_amdgcn_mfma_f32_32x32x16_f16(kf, qf[kd], s[sb], 0, 0, 0);
      }
    }
    __builtin_amdgcn_s_setprio(0);

    float pm = -1e30f;
#pragma unroll
    for (int sb = 0; sb < 2; sb++)
#pragma unroll
      for (int r = 0; r < 16; r++) pm = fmaxf(pm, s[sb][r]);
    pm = fmaxf(pm, __shfl_xor(pm, 32));
    if (!__all(pm <= m + 8.0f)) {
      float mn = fmaxf(m, pm);
      float al = __builtin_amdgcn_exp2f(m - mn);
      m = mn; l *= al;
#pragma unroll
      for (int r = 0; r < 16; r++) { o0[r] *= al; o1[r] *= al; }
    }
    float rs = 0.f;
#pragma unroll
    for (int sb = 0; sb < 2; sb++)
#pragma unroll
      for (int r = 0; r < 16; r++) {
        s[sb][r] = __builtin_amdgcn_exp2f(s[sb][r] - m);
        rs += s[sb][r];
      }
    rs += __shfl_xor(rs, 32);
    l += rs;

    const char* vb2 = (const char*)&Vts[cb][0];
    __builtin_amdgcn_s_setprio(1);
#pragma unroll
    for (int sb = 0; sb < 2; sb++) {
#pragma unroll
      for (int hf = 0; hf < 2; hf++) {
        const int rb = hf * 8;
        unsigned w0a = __builtin_bit_cast(unsigned, __builtin_amdgcn_cvt_pkrtz(s[sb][rb + 0], s[sb][rb + 1]));
        unsigned w0b = __builtin_bit_cast(unsigned, __builtin_amdgcn_cvt_pkrtz(s[sb][rb + 4], s[sb][rb + 5]));
        unsigned w1a = __builtin_bit_cast(unsigned, __builtin_amdgcn_cvt_pkrtz(s[sb][rb + 2], s[sb][rb + 3]));
        unsigned w1b = __builtin_bit_cast(unsigned, __builtin_amdgcn_cvt_pkrtz(s[sb][rb + 6], s[sb][rb + 7]));
        asm("v_permlane32_swap_b32 %0, %1" : "+v"(w0a), "+v"(w0b));
        asm("v_permlane32_swap_b32 %0, %1" : "+v"(w1a), "+v"(w1b));
        uint4v u; u[0] = w0a; u[1] = w1a; u[2] = w0b; u[3] = w1b;
        half8 pf = __builtin_bit_cast(half8, u);
        const int ks = sb * 2 + hf;
        const int ch = ks * 2 + hi;
        half8 vf0 = *reinterpret_cast<const half8*>(vb2 + lo * 128 + ((ch ^ (lo & 7)) * 16));
        half8 vf1 = *reinterpret_cast<const half8*>(vb2 + (lo + 32) * 128 + ((ch ^ (lo & 7)) * 16));
        o0 = __builtin_amdgcn_mfma_f32_32x32x16_f16(vf0, pf, o0, 0, 0, 0);
        o1 = __builtin_amdgcn_mfma_f32_32x32x16_f16(vf1, pf, o1, 0, 0, 0);
      }
    }
    __builtin_amdgcn_s_setprio(0);

    __builtin_amdgcn_sched_barrier(0);
    __builtin_amdgcn_s_barrier();
  }

  float inv = 1.0f / l;
  const int gr = (b * H_ + h) * S_ + qrow;
  _Float16* ob = Opart + ((size_t)sp * NR_ + gr) * 64;
#pragma unroll
  for (int mt = 0; mt < 2; mt++)
#pragma unroll
    for (int rq = 0; rq < 4; rq++) {
      half4 v;
#pragma unroll
      for (int e = 0; e < 4; e++) v[e] = (_Float16)(((mt ? o1 : o0)[4 * rq + e]) * inv);
      *reinterpret_cast<half4*>(ob + 32 * mt + 8 * rq + 4 * hi) = v;
    }
  if (hi == 0) keys[sp * NR_ + gr] = m + __log2f(l);
}

// ---------------------------------------------------------------------------
// Combine the two KV-split halves: out = (w0*O0 + w1*O1)/(w0+w1), wi = 2^keyi
// ---------------------------------------------------------------------------
__global__ __launch_bounds__(256) void flash_combine(const _Float16* __restrict__ Opart,
                                                     const float* __restrict__ keys,
                                                     _Float16* __restrict__ attn_out) {
  const int gr = blockIdx.x * 256 + threadIdx.x;
  const float k0 = keys[gr], k1 = keys[NR_ + gr];
  const float mx = fmaxf(k0, k1);
  const float w0 = __builtin_amdgcn_exp2f(k0 - mx);
  const float w1 = __builtin_amdgcn_exp2f(k1 - mx);
  const float inv = 1.0f / (w0 + w1);
  const float a0 = w0 * inv, a1 = w1 * inv;
  const int bh = gr >> 11, qs = gr & 2047, b = bh >> 4, h = bh & 15;
  const half8* p0 = reinterpret_cast<const half8*>(Opart + (size_t)gr * 64);
  const half8* p1 = reinterpret_cast<const half8*>(Opart + ((size_t)NR_ + gr) * 64);
  half8* ob = reinterpret_cast<half8*>(
      attn_out + ((size_t)(b * S_ + qs)) * D_ + h * 64);
#pragma unroll
  for (int j = 0; j < 8; j++) {
    half8 x0 = p0[j], x1 = p1[j];
    half8 o;
#pragma unroll
    for (int e = 0; e < 8; e++)
      o[e] = (_Float16)(a0 * (float)x0[e] + a1 * (float)x1[e]);
    ob[j] = o;
  }
}

// ---------------------------------------------------------------------------
extern "C" void kernel_launch(void* const* d_in, const int* in_sizes, int n_in,
                              void* d_out, int out_size, void* d_ws, size_t ws_size,
                              hipStream_t stream) {
  const float* x     = (const float*)d_in[0];
  const float* W_qkv = (const float*)d_in[1];
  const float* b_qkv = (const float*)d_in[2];
  const float* W_out = (const float*)d_in[3];
  const float* b_out = (const float*)d_in[4];
  float* out = (float*)d_out;

  _Float16* xh    = (_Float16*)d_ws;
  _Float16* qkvh  = xh + (size_t)M_ * D_;
  _Float16* Vth   = qkvh + (size_t)M_ * 3 * D_;
  _Float16* WoT   = Vth + (size_t)B_ * H_ * 64 * S_;
  _Float16* WqT   = WoT + (size_t)D_ * D_;
  _Float16* Opart = WqT;                                  // alias (WqT dead by flash)
  float*    keys  = (float*)(Opart + (size_t)2 * NR_ * 64);
  _Float16* atth  = xh;                                   // alias (xh dead by combine)

  cast_f32_f16<<<(M_ * D_ / 8 + 255) / 256, 256, 0, stream>>>(x, xh, M_ * D_ / 8);
  transpose_cast<<<dim3(3 * D_ / 64, D_ / 64), 256, 0, stream>>>(W_qkv, WqT, D_, 3 * D_);
  transpose_cast<<<dim3(D_ / 64, D_ / 64), 256, 0, stream>>>(W_out, WoT, D_, D_);

  // QKV projection: 8-phase 256^2 kernel, grid (3072/256)*(4096/256) = 192
  gemm256_mfma<<<192, 512, 131072, stream>>>(
      xh, WqT, b_qkv, qkvh, M_, 3 * D_, D_, QSCALE, D_);

  v_transpose<<<dim3(S_ / 64, B_ * H_), 256, 0, stream>>>(qkvh, Vth);

  flash_mfma<<<dim3(S_ / 128, H_, B_ * 2), 256, 0, stream>>>(qkvh, Vth, Opart, keys);

  flash_combine<<<NR_ / 256, 256, 0, stream>>>(Opart, keys, atth);

  gemm_mfma<false><<<dim3(D_ / 128, M_ / 128), 256, 0, stream>>>(
      atth, WoT, b_out, out, M_, D_, D_, 1.0f, 0);
}

// Round 8
// 143.385 us; speedup vs baseline: 1.0793x; 1.0419x over previous
//
#include <hip/hip_runtime.h>

typedef _Float16 half8  __attribute__((ext_vector_type(8)));
typedef _Float16 half4  __attribute__((ext_vector_type(4)));
typedef float    floatx4  __attribute__((ext_vector_type(4)));
typedef float    floatx16 __attribute__((ext_vector_type(16)));
typedef unsigned int uint4v __attribute__((ext_vector_type(4)));

constexpr int B_ = 2, S_ = 2048, D_ = 1024, H_ = 16, M_ = 4096;
constexpr int NR_ = B_ * H_ * S_;               // 65536 (b,h,s) rows
constexpr float QSCALE = 0.18033688011112042f;  // log2(e)/8
constexpr int KVB = 64;                         // kv tile
constexpr int HT = 16;                          // tiles per half (1024/64)

__device__ __forceinline__ void gload16(const void* g, void* l) {
  __builtin_amdgcn_global_load_lds((const __attribute__((address_space(1))) void*)g,
                                   (__attribute__((address_space(3))) void*)l, 16, 0, 0);
}

// ---------------------------------------------------------------------------
// cast fp32 -> fp16, 8 elems/thread
// ---------------------------------------------------------------------------
__global__ __launch_bounds__(256) void cast_f32_f16(const float* __restrict__ in,
                                                    _Float16* __restrict__ out, int n8) {
  int i = blockIdx.x * 256 + threadIdx.x;
  if (i >= n8) return;
  float4 a = reinterpret_cast<const float4*>(in)[2 * i];
  float4 b = reinterpret_cast<const float4*>(in)[2 * i + 1];
  half8 h;
  h[0] = (_Float16)a.x; h[1] = (_Float16)a.y; h[2] = (_Float16)a.z; h[3] = (_Float16)a.w;
  h[4] = (_Float16)b.x; h[5] = (_Float16)b.y; h[6] = (_Float16)b.z; h[7] = (_Float16)b.w;
  reinterpret_cast<half8*>(out)[i] = h;
}

// ---------------------------------------------------------------------------
// W[K][N] fp32 -> WT[N][K] fp16 (64x64 tiles)
// ---------------------------------------------------------------------------
__global__ __launch_bounds__(256) void transpose_cast(const float* __restrict__ W,
                                                      _Float16* __restrict__ WT,
                                                      int K, int N) {
  __shared__ float Ws[64][65];
  const int n0 = blockIdx.x * 64, k0 = blockIdx.y * 64;
  const int t = threadIdx.x;
#pragma unroll
  for (int i = 0; i < 4; i++) {
    int idx = t + 256 * i;
    int r = idx >> 4, c4 = idx & 15;
    float4 v = *reinterpret_cast<const float4*>(W + (size_t)(k0 + r) * N + n0 + c4 * 4);
    Ws[r][c4 * 4 + 0] = v.x; Ws[r][c4 * 4 + 1] = v.y;
    Ws[r][c4 * 4 + 2] = v.z; Ws[r][c4 * 4 + 3] = v.w;
  }
  __syncthreads();
#pragma unroll
  for (int i = 0; i < 2; i++) {
    int idx = t + 256 * i;
    int r = idx >> 3, ck = idx & 7;
    half8 h;
#pragma unroll
    for (int j = 0; j < 8; j++) h[j] = (_Float16)Ws[ck * 8 + j][r];
    *reinterpret_cast<half8*>(WT + (size_t)(n0 + r) * K + k0 + ck * 8) = h;
  }
}

// ---------------------------------------------------------------------------
// 256x256 fp16 MFMA GEMM, double-buffered, counted vmcnt(8).
// 512 thr = 8 waves (2M x 4N); BK=64; 128 KiB LDS (dynamic).
// RACE FENCES (rule #18): s_barrier is NOT a compiler memory fence —
// sched_barrier(0) required after the publishing barrier (blocks ds_read
// hoist above it) and before the trailing barrier (blocks sink below it).
// ---------------------------------------------------------------------------
__global__ __launch_bounds__(512, 2) void gemm256_mfma(
    const _Float16* __restrict__ A, const _Float16* __restrict__ BT,
    const float* __restrict__ bias, _Float16* __restrict__ Cout,
    int M, int N, int K, float scale_lo, int ncut) {
  extern __shared__ char smem[];   // 131072 B: As[2][32KB] | Bs[2][32KB]
  const int tid = threadIdx.x, w = tid >> 6, lane = tid & 63;
  const int wm = w >> 2, wn = w & 3;

  // XCD-aware bijective swizzle over flat grid
  const int nwg = gridDim.x, cpx = nwg >> 3;
  const int wg = (blockIdx.x & 7) * cpx + (blockIdx.x >> 3);
  const int nbx = N >> 8;
  const int bx = wg % nbx, by = wg / nbx;
  const int m0 = by * 256, n0 = bx * 256;

  const int NT = K >> 6;

  auto stage = [&](int buf, int kt) {
    const int k0 = kt * 64;
    char* Ad = smem + buf * 32768;
    char* Bd = smem + 65536 + buf * 32768;
#pragma unroll
    for (int i = 0; i < 4; i++) {
      int idx = tid + 512 * i;
      int r = idx >> 3, c = idx & 7, cs = c ^ (r & 7);
      gload16(A + (size_t)(m0 + r) * K + k0 + cs * 8, Ad + idx * 16);
    }
#pragma unroll
    for (int i = 0; i < 4; i++) {
      int idx = tid + 512 * i;
      int r = idx >> 3, c = idx & 7, cs = c ^ (r & 7);
      gload16(BT + (size_t)(n0 + r) * K + k0 + cs * 8, Bd + idx * 16);
    }
  };

  floatx4 acc[8][4] = {};

  stage(0, 0);

  for (int kt = 0; kt < NT; ++kt) {
    const int p = kt & 1;
    if (kt + 1 < NT) {
      stage(p ^ 1, kt + 1);                            // issue next tile first
      asm volatile("s_waitcnt vmcnt(8)" ::: "memory"); // this tile landed; next in flight
    } else {
      asm volatile("s_waitcnt vmcnt(0)" ::: "memory"); // last tile: drain
    }
    __builtin_amdgcn_s_barrier();
    __builtin_amdgcn_sched_barrier(0);   // no ds_read hoist above the barrier

    const char* Ab = smem + p * 32768;
    const char* Bb = smem + 65536 + p * 32768;
#pragma unroll
    for (int q = 0; q < 4; q++) {
      half8 af[2][2], bf[4][2];
#pragma unroll
      for (int e = 0; e < 2; e++)
#pragma unroll
        for (int ks = 0; ks < 2; ks++) {
          int row = wm * 128 + (2 * q + e) * 16 + (lane & 15);
          int ch = (ks * 4 + (lane >> 4)) ^ (row & 7);
          af[e][ks] = *reinterpret_cast<const half8*>(Ab + row * 128 + ch * 16);
        }
#pragma unroll
      for (int n = 0; n < 4; n++)
#pragma unroll
        for (int ks = 0; ks < 2; ks++) {
          int row = wn * 64 + n * 16 + (lane & 15);
          int ch = (ks * 4 + (lane >> 4)) ^ (row & 7);
          bf[n][ks] = *reinterpret_cast<const half8*>(Bb + row * 128 + ch * 16);
        }
      __builtin_amdgcn_s_setprio(1);
#pragma unroll
      for (int ks = 0; ks < 2; ks++)
#pragma unroll
        for (int e = 0; e < 2; e++)
#pragma unroll
          for (int n = 0; n < 4; n++)
            acc[2 * q + e][n] = __builtin_amdgcn_mfma_f32_16x16x32_f16(
                af[e][ks], bf[n][ks], acc[2 * q + e][n], 0, 0, 0);
      __builtin_amdgcn_s_setprio(0);
    }
    __builtin_amdgcn_sched_barrier(0);   // no ds_read sink below the barrier
    __builtin_amdgcn_s_barrier();        // all reads of buffer p done before overwrite
  }

#pragma unroll
  for (int mf = 0; mf < 8; mf++)
#pragma unroll
    for (int n = 0; n < 4; n++) {
      int col = n0 + wn * 64 + n * 16 + (lane & 15);
      float bv = bias[col];
      float sc = (col < ncut) ? scale_lo : 1.0f;
#pragma unroll
      for (int reg = 0; reg < 4; reg++) {
        int row = m0 + wm * 128 + mf * 16 + (lane >> 4) * 4 + reg;
        Cout[(size_t)row * N + col] = (_Float16)((acc[mf][n][reg] + bv) * sc);
      }
    }
}

// ---------------------------------------------------------------------------
// fp16 MFMA GEMM, 128x128 tile (m97-class) — used for the output projection
// (__syncthreads drains vmcnt/lgkmcnt — inherently fence-safe)
// ---------------------------------------------------------------------------
template <bool OUT_HALF>
__global__ __launch_bounds__(256) void gemm_mfma(const _Float16* __restrict__ A,
                                                 const _Float16* __restrict__ BT,
                                                 const float* __restrict__ bias,
                                                 void* __restrict__ Cout,
                                                 int M, int N, int K,
                                                 float scale_lo, int ncut) {
  __shared__ _Float16 As[128 * 64];
  __shared__ _Float16 Bs[128 * 64];
  const int t = threadIdx.x, w = t >> 6, lane = t & 63;
  const int m0 = blockIdx.y * 128, n0 = blockIdx.x * 128;
  const int wr = (w >> 1) * 64, wc = (w & 1) * 64;

  floatx4 acc[4][4] = {};

  for (int k0 = 0; k0 < K; k0 += 64) {
    __syncthreads();
#pragma unroll
    for (int i = 0; i < 4; i++) {
      int idx = t + 256 * i;
      int r = idx >> 3, c = idx & 7;
      int cs = c ^ (r & 7);
      gload16(A + (size_t)(m0 + r) * K + k0 + cs * 8, (char*)As + idx * 16);
      gload16(BT + (size_t)(n0 + r) * K + k0 + cs * 8, (char*)Bs + idx * 16);
    }
    __syncthreads();
#pragma unroll
    for (int ks = 0; ks < 2; ks++) {
      half8 af[4], bf[4];
#pragma unroll
      for (int r = 0; r < 4; r++) {
        int row = wr + r * 16 + (lane & 15);
        int ch = (ks * 4 + (lane >> 4)) ^ (row & 7);
        af[r] = *reinterpret_cast<const half8*>((const char*)As + row * 128 + ch * 16);
      }
#pragma unroll
      for (int c = 0; c < 4; c++) {
        int row = wc + c * 16 + (lane & 15);
        int ch = (ks * 4 + (lane >> 4)) ^ (row & 7);
        bf[c] = *reinterpret_cast<const half8*>((const char*)Bs + row * 128 + ch * 16);
      }
#pragma unroll
      for (int r = 0; r < 4; r++)
#pragma unroll
        for (int c = 0; c < 4; c++)
          acc[r][c] = __builtin_amdgcn_mfma_f32_16x16x32_f16(af[r], bf[c], acc[r][c], 0, 0, 0);
    }
  }

#pragma unroll
  for (int r = 0; r < 4; r++)
#pragma unroll
    for (int c = 0; c < 4; c++) {
      int col = n0 + wc + c * 16 + (lane & 15);
      float bv = bias[col];
      float sc = (col < ncut) ? scale_lo : 1.0f;
#pragma unroll
      for (int reg = 0; reg < 4; reg++) {
        int row = m0 + wr + r * 16 + (lane >> 4) * 4 + reg;
        float v = (acc[r][c][reg] + bv) * sc;
        if (OUT_HALF)
          reinterpret_cast<_Float16*>(Cout)[(size_t)row * N + col] = (_Float16)v;
        else
          reinterpret_cast<float*>(Cout)[(size_t)row * N + col] = v;
      }
    }
}

// ---------------------------------------------------------------------------
// V transpose: qkv[B*S][3D] fp16 (V slice) -> Vt[(b*H+h)*64 + d][S] fp16
// ---------------------------------------------------------------------------
__global__ __launch_bounds__(256) void v_transpose(const _Float16* __restrict__ qkv,
                                                   _Float16* __restrict__ Vt) {
  __shared__ _Float16 Vs[64][72];
  const int s0 = blockIdx.x * 64, bh = blockIdx.y;
  const int b = bh >> 4, h = bh & 15;
  const int t = threadIdx.x;
#pragma unroll
  for (int i = 0; i < 2; i++) {
    int idx = t + 256 * i;
    int r = idx >> 3, c = idx & 7;
    half8 v = *reinterpret_cast<const half8*>(
        qkv + (size_t)(b * S_ + s0 + r) * (3 * D_) + 2 * D_ + h * 64 + c * 8);
    *reinterpret_cast<half8*>(&Vs[r][c * 8]) = v;
  }
  __syncthreads();
#pragma unroll
  for (int i = 0; i < 2; i++) {
    int idx = t + 256 * i;
    int d = idx >> 3, c = idx & 7;
    half8 o;
#pragma unroll
    for (int j = 0; j < 8; j++) o[j] = Vs[c * 8 + j][d];
    *reinterpret_cast<half8*>(Vt + ((size_t)bh * 64 + d) * S_ + s0 + c * 8) = o;
  }
}

// ---------------------------------------------------------------------------
// Flash attention, fp16 MFMA 32x32x16, KVB=64 double-buffered, KV-SPLIT x2.
// launch_bounds(256,3) occupancy; early P->fp16 (register pressure);
// sched_barrier(0) fences restored at both barrier edges (rule #18 race fix).
// ---------------------------------------------------------------------------
__global__ __launch_bounds__(256, 3) void flash_mfma(const _Float16* __restrict__ qkv,
                                                     const _Float16* __restrict__ Vt,
                                                     _Float16* __restrict__ Opart,
                                                     float* __restrict__ keys) {
  const int qt = blockIdx.x, h = blockIdx.y;
  const int b = blockIdx.z >> 1, sp = blockIdx.z & 1;
  const int t = threadIdx.x, w = t >> 6, lane = t & 63;
  const int lo = lane & 31, hi = lane >> 5;

  __shared__ _Float16 Ks[2][KVB * 64];    // [kk][d] rows 128B, chunk^(r&7)
  __shared__ _Float16 Vts[2][64 * KVB];   // [d][kk] rows 128B, chunk^(r&7)

  const int qrow = qt * 128 + w * 32 + lo;
  const _Float16* qbase = qkv + (size_t)(b * S_ + qrow) * (3 * D_) + h * 64;
  half8 qf[4];
#pragma unroll
  for (int kd = 0; kd < 4; kd++)
    qf[kd] = *reinterpret_cast<const half8*>(qbase + kd * 16 + hi * 8);
  asm volatile("" : "+v"(qf[0]), "+v"(qf[1]), "+v"(qf[2]), "+v"(qf[3]));

  const size_t kbase = (size_t)(b * S_) * (3 * D_) + D_ + h * 64;
  const size_t vbase = (size_t)(b * H_ + h) * 64 * S_;
  const int kvbase = sp * (S_ / 2);

  auto stage = [&](int buf, int tile) {
    const int kv0 = kvbase + tile * KVB;
    const _Float16* kg = qkv + kbase + (size_t)kv0 * (3 * D_);
#pragma unroll
    for (int p = 0; p < 2; p++) {
      int idx = t + 256 * p;
      int r = idx >> 3, c = idx & 7, cs = c ^ (r & 7);
      gload16(kg + (size_t)r * (3 * D_) + cs * 8, (char*)&Ks[buf][0] + idx * 16);
    }
    const _Float16* vg = Vt + vbase + kv0;
#pragma unroll
    for (int p = 0; p < 2; p++) {
      int idx = t + 256 * p;
      int r = idx >> 3, c = idx & 7, cs = c ^ (r & 7);
      gload16(vg + (size_t)r * S_ + cs * 8, (char*)&Vts[buf][0] + idx * 16);
    }
  };

  floatx16 o0, o1;
#pragma unroll
  for (int r = 0; r < 16; r++) { o0[r] = 0.f; o1[r] = 0.f; }
  float m = -1e30f, l = 0.f;

  stage(0, 0);

  for (int tt = 0; tt < HT; ++tt) {
    const int cb = tt & 1;
    stage(cb ^ 1, (tt + 1) & (HT - 1));
    asm volatile("s_waitcnt vmcnt(4)" ::: "memory");
    __builtin_amdgcn_s_barrier();
    __builtin_amdgcn_sched_barrier(0);   // no ds_read hoist above the barrier

    // ---- S^T = K @ Q^T : lane holds q=lo
    const char* kb2 = (const char*)&Ks[cb][0];
    floatx16 s0v, s1v;
#pragma unroll
    for (int r = 0; r < 16; r++) { s0v[r] = 0.f; s1v[r] = 0.f; }
    __builtin_amdgcn_s_setprio(1);
#pragma unroll
    for (int kd = 0; kd < 4; kd++) {
      int r0 = lo, r1 = 32 + lo;
      half8 k0f = *reinterpret_cast<const half8*>(
          kb2 + r0 * 128 + (((kd * 2 + hi) ^ (r0 & 7)) * 16));
      half8 k1f = *reinterpret_cast<const half8*>(
          kb2 + r1 * 128 + (((kd * 2 + hi) ^ (r1 & 7)) * 16));
      s0v = __builtin_amdgcn_mfma_f32_32x32x16_f16(k0f, qf[kd], s0v, 0, 0, 0);
      s1v = __builtin_amdgcn_mfma_f32_32x32x16_f16(k1f, qf[kd], s1v, 0, 0, 0);
    }
    __builtin_amdgcn_s_setprio(0);

    // ---- online softmax (exp2 domain), defer-max THR=8
    float pm = -1e30f;
#pragma unroll
    for (int r = 0; r < 16; r++) pm = fmaxf(pm, fmaxf(s0v[r], s1v[r]));
    pm = fmaxf(pm, __shfl_xor(pm, 32));
    if (!__all(pm <= m + 8.0f)) {
      float mn = fmaxf(m, pm);
      float al = __builtin_amdgcn_exp2f(m - mn);
      m = mn; l *= al;
#pragma unroll
      for (int r = 0; r < 16; r++) { o0[r] *= al; o1[r] *= al; }
    }
    float rs = 0.f;
#pragma unroll
    for (int r = 0; r < 16; r++) {
      s0v[r] = __builtin_amdgcn_exp2f(s0v[r] - m);
      s1v[r] = __builtin_amdgcn_exp2f(s1v[r] - m);
      rs += s0v[r] + s1v[r];
    }
    rs += __shfl_xor(rs, 32);
    l += rs;

    // ---- convert P to fp16 B-fragments NOW (frees the 32 f32 score regs)
    half8 pf0a, pf0b, pf1a, pf1b;
    {
      unsigned a0 = __builtin_bit_cast(unsigned, __builtin_amdgcn_cvt_pkrtz(s0v[0], s0v[1]));
      unsigned b0 = __builtin_bit_cast(unsigned, __builtin_amdgcn_cvt_pkrtz(s0v[4], s0v[5]));
      unsigned a1 = __builtin_bit_cast(unsigned, __builtin_amdgcn_cvt_pkrtz(s0v[2], s0v[3]));
      unsigned b1 = __builtin_bit_cast(unsigned, __builtin_amdgcn_cvt_pkrtz(s0v[6], s0v[7]));
      asm("v_permlane32_swap_b32 %0, %1" : "+v"(a0), "+v"(b0));
      asm("v_permlane32_swap_b32 %0, %1" : "+v"(a1), "+v"(b1));
      uint4v u; u[0] = a0; u[1] = a1; u[2] = b0; u[3] = b1;
      pf0a = __builtin_bit_cast(half8, u);
      a0 = __builtin_bit_cast(unsigned, __builtin_amdgcn_cvt_pkrtz(s0v[8], s0v[9]));
      b0 = __builtin_bit_cast(unsigned, __builtin_amdgcn_cvt_pkrtz(s0v[12], s0v[13]));
      a1 = __builtin_bit_cast(unsigned, __builtin_amdgcn_cvt_pkrtz(s0v[10], s0v[11]));
      b1 = __builtin_bit_cast(unsigned, __builtin_amdgcn_cvt_pkrtz(s0v[14], s0v[15]));
      asm("v_permlane32_swap_b32 %0, %1" : "+v"(a0), "+v"(b0));
      asm("v_permlane32_swap_b32 %0, %1" : "+v"(a1), "+v"(b1));
      u[0] = a0; u[1] = a1; u[2] = b0; u[3] = b1;
      pf0b = __builtin_bit_cast(half8, u);
      a0 = __builtin_bit_cast(unsigned, __builtin_amdgcn_cvt_pkrtz(s1v[0], s1v[1]));
      b0 = __builtin_bit_cast(unsigned, __builtin_amdgcn_cvt_pkrtz(s1v[4], s1v[5]));
      a1 = __builtin_bit_cast(unsigned, __builtin_amdgcn_cvt_pkrtz(s1v[2], s1v[3]));
      b1 = __builtin_bit_cast(unsigned, __builtin_amdgcn_cvt_pkrtz(s1v[6], s1v[7]));
      asm("v_permlane32_swap_b32 %0, %1" : "+v"(a0), "+v"(b0));
      asm("v_permlane32_swap_b32 %0, %1" : "+v"(a1), "+v"(b1));
      u[0] = a0; u[1] = a1; u[2] = b0; u[3] = b1;
      pf1a = __builtin_bit_cast(half8, u);
      a0 = __builtin_bit_cast(unsigned, __builtin_amdgcn_cvt_pkrtz(s1v[8], s1v[9]));
      b0 = __builtin_bit_cast(unsigned, __builtin_amdgcn_cvt_pkrtz(s1v[12], s1v[13]));
      a1 = __builtin_bit_cast(unsigned, __builtin_amdgcn_cvt_pkrtz(s1v[10], s1v[11]));
      b1 = __builtin_bit_cast(unsigned, __builtin_amdgcn_cvt_pkrtz(s1v[14], s1v[15]));
      asm("v_permlane32_swap_b32 %0, %1" : "+v"(a0), "+v"(b0));
      asm("v_permlane32_swap_b32 %0, %1" : "+v"(a1), "+v"(b1));
      u[0] = a0; u[1] = a1; u[2] = b0; u[3] = b1;
      pf1b = __builtin_bit_cast(half8, u);
    }

    // ---- O^T += V^T @ P^T
    const char* vb2 = (const char*)&Vts[cb][0];
    __builtin_amdgcn_s_setprio(1);
#pragma unroll
    for (int ks = 0; ks < 4; ks++) {
      half8 pf = (ks == 0) ? pf0a : (ks == 1) ? pf0b : (ks == 2) ? pf1a : pf1b;
      const int ch = ks * 2 + hi;
      half8 vf0 = *reinterpret_cast<const half8*>(vb2 + lo * 128 + ((ch ^ (lo & 7)) * 16));
      half8 vf1 = *reinterpret_cast<const half8*>(vb2 + (lo + 32) * 128 + ((ch ^ (lo & 7)) * 16));
      o0 = __builtin_amdgcn_mfma_f32_32x32x16_f16(vf0, pf, o0, 0, 0, 0);
      o1 = __builtin_amdgcn_mfma_f32_32x32x16_f16(vf1, pf, o1, 0, 0, 0);
    }
    __builtin_amdgcn_s_setprio(0);

    __builtin_amdgcn_sched_barrier(0);   // no ds_read sink below the barrier
    __builtin_amdgcn_s_barrier();
  }

  float inv = 1.0f / l;
  const int gr = (b * H_ + h) * S_ + qrow;
  _Float16* ob = Opart + ((size_t)sp * NR_ + gr) * 64;
#pragma unroll
  for (int mt = 0; mt < 2; mt++)
#pragma unroll
    for (int rq = 0; rq < 4; rq++) {
      half4 v;
#pragma unroll
      for (int e = 0; e < 4; e++) v[e] = (_Float16)(((mt ? o1 : o0)[4 * rq + e]) * inv);
      *reinterpret_cast<half4*>(ob + 32 * mt + 8 * rq + 4 * hi) = v;
    }
  if (hi == 0) keys[sp * NR_ + gr] = m + __log2f(l);
}

// ---------------------------------------------------------------------------
// Combine the two KV-split halves: out = (w0*O0 + w1*O1)/(w0+w1), wi = 2^keyi
// ---------------------------------------------------------------------------
__global__ __launch_bounds__(256) void flash_combine(const _Float16* __restrict__ Opart,
                                                     const float* __restrict__ keys,
                                                     _Float16* __restrict__ attn_out) {
  const int gr = blockIdx.x * 256 + threadIdx.x;
  const float k0 = keys[gr], k1 = keys[NR_ + gr];
  const float mx = fmaxf(k0, k1);
  const float w0 = __builtin_amdgcn_exp2f(k0 - mx);
  const float w1 = __builtin_amdgcn_exp2f(k1 - mx);
  const float inv = 1.0f / (w0 + w1);
  const float a0 = w0 * inv, a1 = w1 * inv;
  const int bh = gr >> 11, qs = gr & 2047, b = bh >> 4, h = bh & 15;
  const half8* p0 = reinterpret_cast<const half8*>(Opart + (size_t)gr * 64);
  const half8* p1 = reinterpret_cast<const half8*>(Opart + ((size_t)NR_ + gr) * 64);
  half8* ob = reinterpret_cast<half8*>(
      attn_out + ((size_t)(b * S_ + qs)) * D_ + h * 64);
#pragma unroll
  for (int j = 0; j < 8; j++) {
    half8 x0 = p0[j], x1 = p1[j];
    half8 o;
#pragma unroll
    for (int e = 0; e < 8; e++)
      o[e] = (_Float16)(a0 * (float)x0[e] + a1 * (float)x1[e]);
    ob[j] = o;
  }
}

// ---------------------------------------------------------------------------
extern "C" void kernel_launch(void* const* d_in, const int* in_sizes, int n_in,
                              void* d_out, int out_size, void* d_ws, size_t ws_size,
                              hipStream_t stream) {
  const float* x     = (const float*)d_in[0];
  const float* W_qkv = (const float*)d_in[1];
  const float* b_qkv = (const float*)d_in[2];
  const float* W_out = (const float*)d_in[3];
  const float* b_out = (const float*)d_in[4];
  float* out = (float*)d_out;

  _Float16* xh    = (_Float16*)d_ws;
  _Float16* qkvh  = xh + (size_t)M_ * D_;
  _Float16* Vth   = qkvh + (size_t)M_ * 3 * D_;
  _Float16* WoT   = Vth + (size_t)B_ * H_ * 64 * S_;
  _Float16* WqT   = WoT + (size_t)D_ * D_;
  _Float16* Opart = WqT;                                  // alias (WqT dead by flash)
  float*    keys  = (float*)(Opart + (size_t)2 * NR_ * 64);
  _Float16* atth  = xh;                                   // alias (xh dead by combine)

  cast_f32_f16<<<(M_ * D_ / 8 + 255) / 256, 256, 0, stream>>>(x, xh, M_ * D_ / 8);
  transpose_cast<<<dim3(3 * D_ / 64, D_ / 64), 256, 0, stream>>>(W_qkv, WqT, D_, 3 * D_);
  transpose_cast<<<dim3(D_ / 64, D_ / 64), 256, 0, stream>>>(W_out, WoT, D_, D_);

  gemm256_mfma<<<192, 512, 131072, stream>>>(
      xh, WqT, b_qkv, qkvh, M_, 3 * D_, D_, QSCALE, D_);

  v_transpose<<<dim3(S_ / 64, B_ * H_), 256, 0, stream>>>(qkvh, Vth);

  flash_mfma<<<dim3(S_ / 128, H_, B_ * 2), 256, 0, stream>>>(qkvh, Vth, Opart, keys);

  flash_combine<<<NR_ / 256, 256, 0, stream>>>(Opart, keys, atth);

  gemm_mfma<false><<<dim3(D_ / 128, M_ / 128), 256, 0, stream>>>(
      atth, WoT, b_out, out, M_, D_, D_, 1.0f, 0);
}

// Round 9
// 137.053 us; speedup vs baseline: 1.1292x; 1.0462x over previous
//
#include <hip/hip_runtime.h>

typedef _Float16 half8  __attribute__((ext_vector_type(8)));
typedef _Float16 half4  __attribute__((ext_vector_type(4)));
typedef float    floatx4  __attribute__((ext_vector_type(4)));
typedef float    floatx16 __attribute__((ext_vector_type(16)));
typedef unsigned int uint4v __attribute__((ext_vector_type(4)));

constexpr int B_ = 2, S_ = 2048, D_ = 1024, H_ = 16, M_ = 4096;
constexpr int NR_ = B_ * H_ * S_;               // 65536 (b,h,s) rows
constexpr float QSCALE = 0.18033688011112042f;  // log2(e)/8
constexpr int KVB = 64;                         // kv tile
constexpr int HT = 16;                          // tiles per half (1024/64)

__device__ __forceinline__ void gload16(const void* g, void* l) {
  __builtin_amdgcn_global_load_lds((const __attribute__((address_space(1))) void*)g,
                                   (__attribute__((address_space(3))) void*)l, 16, 0, 0);
}

// ---------------------------------------------------------------------------
// cast fp32 -> fp16, 8 elems/thread
// ---------------------------------------------------------------------------
__global__ __launch_bounds__(256) void cast_f32_f16(const float* __restrict__ in,
                                                    _Float16* __restrict__ out, int n8) {
  int i = blockIdx.x * 256 + threadIdx.x;
  if (i >= n8) return;
  float4 a = reinterpret_cast<const float4*>(in)[2 * i];
  float4 b = reinterpret_cast<const float4*>(in)[2 * i + 1];
  half8 h;
  h[0] = (_Float16)a.x; h[1] = (_Float16)a.y; h[2] = (_Float16)a.z; h[3] = (_Float16)a.w;
  h[4] = (_Float16)b.x; h[5] = (_Float16)b.y; h[6] = (_Float16)b.z; h[7] = (_Float16)b.w;
  reinterpret_cast<half8*>(out)[i] = h;
}

// ---------------------------------------------------------------------------
// W[K][N] fp32 -> WT[N][K] fp16 (64x64 tiles). z selects {W_qkv, W_out}.
// ---------------------------------------------------------------------------
__global__ __launch_bounds__(256) void transpose_cast2(const float* __restrict__ W0,
                                                       _Float16* __restrict__ WT0,
                                                       const float* __restrict__ W1,
                                                       _Float16* __restrict__ WT1) {
  __shared__ float Ws[64][65];
  const int z = blockIdx.z;
  const int NW = z ? D_ : 3 * D_;
  if (blockIdx.x * 64 >= NW) return;
  const float* W = z ? W1 : W0;
  _Float16* WT = z ? WT1 : WT0;
  const int K = D_, N = NW;
  const int n0 = blockIdx.x * 64, k0 = blockIdx.y * 64;
  const int t = threadIdx.x;
#pragma unroll
  for (int i = 0; i < 4; i++) {
    int idx = t + 256 * i;
    int r = idx >> 4, c4 = idx & 15;
    float4 v = *reinterpret_cast<const float4*>(W + (size_t)(k0 + r) * N + n0 + c4 * 4);
    Ws[r][c4 * 4 + 0] = v.x; Ws[r][c4 * 4 + 1] = v.y;
    Ws[r][c4 * 4 + 2] = v.z; Ws[r][c4 * 4 + 3] = v.w;
  }
  __syncthreads();
#pragma unroll
  for (int i = 0; i < 2; i++) {
    int idx = t + 256 * i;
    int r = idx >> 3, ck = idx & 7;
    half8 h;
#pragma unroll
    for (int j = 0; j < 8; j++) h[j] = (_Float16)Ws[ck * 8 + j][r];
    *reinterpret_cast<half8*>(WT + (size_t)(n0 + r) * K + k0 + ck * 8) = h;
  }
}

// ---------------------------------------------------------------------------
// 256x192 fp16 MFMA GEMM, double-buffered, counted vmcnt(7).
// 512 thr = 8 waves (2M x 4N, 48 cols/wave); BK=64; 112 KiB LDS (dynamic).
// BN=192: grid = (4096/256)x(3072/192) = 16x16 = 256 blocks = 1/CU FULL FILL
// (BN=256 gave 192 blocks -> 25% CUs idle). Sync structure identical to the
// race-proven R8 kernel: STAGE(next) -> vmcnt(7) -> s_barrier+sched_barrier
// -> 4 quadrants {ds_read, setprio MFMA} -> sched_barrier+s_barrier.
// ---------------------------------------------------------------------------
__global__ __launch_bounds__(512, 2) void gemm256_mfma(
    const _Float16* __restrict__ A, const _Float16* __restrict__ BT,
    const float* __restrict__ bias, _Float16* __restrict__ Cout,
    int M, int N, int K, float scale_lo, int ncut) {
  extern __shared__ char smem[];   // 114688 B: As[2][32K] | Bs[2][24K]
  const int tid = threadIdx.x, w = tid >> 6, lane = tid & 63;
  const int wm = w >> 2, wn = w & 3;

  // XCD-aware bijective swizzle over flat grid (nwg = 256, % 8 == 0)
  const int nwg = gridDim.x, cpx = nwg >> 3;
  const int wg = (blockIdx.x & 7) * cpx + (blockIdx.x >> 3);
  const int nbx = N / 192;
  const int bx = wg % nbx, by = wg / nbx;
  const int m0 = by * 256, n0 = bx * 192;

  const int NT = K >> 6;

  auto stage = [&](int buf, int kt) {
    const int k0 = kt * 64;
    char* Ad = smem + buf * 32768;
    char* Bd = smem + 65536 + buf * 24576;
#pragma unroll
    for (int i = 0; i < 4; i++) {              // A: 256 rows x 8 chunks = 2048
      int idx = tid + 512 * i;
      int r = idx >> 3, c = idx & 7, cs = c ^ (r & 7);
      gload16(A + (size_t)(m0 + r) * K + k0 + cs * 8, Ad + idx * 16);
    }
#pragma unroll
    for (int i = 0; i < 3; i++) {              // B: 192 rows x 8 chunks = 1536
      int idx = tid + 512 * i;
      int r = idx >> 3, c = idx & 7, cs = c ^ (r & 7);
      gload16(BT + (size_t)(n0 + r) * K + k0 + cs * 8, Bd + idx * 16);
    }
  };

  floatx4 acc[8][3] = {};

  stage(0, 0);

  for (int kt = 0; kt < NT; ++kt) {
    const int p = kt & 1;
    if (kt + 1 < NT) {
      stage(p ^ 1, kt + 1);                            // issue next tile first
      asm volatile("s_waitcnt vmcnt(7)" ::: "memory"); // this tile landed; next in flight
    } else {
      asm volatile("s_waitcnt vmcnt(0)" ::: "memory"); // last tile: drain
    }
    __builtin_amdgcn_s_barrier();
    __builtin_amdgcn_sched_barrier(0);   // no ds_read hoist above the barrier

    const char* Ab = smem + p * 32768;
    const char* Bb = smem + 65536 + p * 24576;
#pragma unroll
    for (int q = 0; q < 4; q++) {
      half8 af[2][2], bf[3][2];
#pragma unroll
      for (int e = 0; e < 2; e++)
#pragma unroll
        for (int ks = 0; ks < 2; ks++) {
          int row = wm * 128 + (2 * q + e) * 16 + (lane & 15);
          int ch = (ks * 4 + (lane >> 4)) ^ (row & 7);
          af[e][ks] = *reinterpret_cast<const half8*>(Ab + row * 128 + ch * 16);
        }
#pragma unroll
      for (int n = 0; n < 3; n++)
#pragma unroll
        for (int ks = 0; ks < 2; ks++) {
          int row = wn * 48 + n * 16 + (lane & 15);
          int ch = (ks * 4 + (lane >> 4)) ^ (row & 7);
          bf[n][ks] = *reinterpret_cast<const half8*>(Bb + row * 128 + ch * 16);
        }
      __builtin_amdgcn_s_setprio(1);
#pragma unroll
      for (int ks = 0; ks < 2; ks++)
#pragma unroll
        for (int e = 0; e < 2; e++)
#pragma unroll
          for (int n = 0; n < 3; n++)
            acc[2 * q + e][n] = __builtin_amdgcn_mfma_f32_16x16x32_f16(
                af[e][ks], bf[n][ks], acc[2 * q + e][n], 0, 0, 0);
      __builtin_amdgcn_s_setprio(0);
    }
    __builtin_amdgcn_sched_barrier(0);   // no ds_read sink below the barrier
    __builtin_amdgcn_s_barrier();        // all reads of buffer p done before overwrite
  }

#pragma unroll
  for (int mf = 0; mf < 8; mf++)
#pragma unroll
    for (int n = 0; n < 3; n++) {
      int col = n0 + wn * 48 + n * 16 + (lane & 15);
      float bv = bias[col];
      float sc = (col < ncut) ? scale_lo : 1.0f;
#pragma unroll
      for (int reg = 0; reg < 4; reg++) {
        int row = m0 + wm * 128 + mf * 16 + (lane >> 4) * 4 + reg;
        Cout[(size_t)row * N + col] = (_Float16)((acc[mf][n][reg] + bv) * sc);
      }
    }
}

// ---------------------------------------------------------------------------
// fp16 MFMA GEMM, 128x128 tile (m97-class) — used for the output projection
// ---------------------------------------------------------------------------
template <bool OUT_HALF>
__global__ __launch_bounds__(256) void gemm_mfma(const _Float16* __restrict__ A,
                                                 const _Float16* __restrict__ BT,
                                                 const float* __restrict__ bias,
                                                 void* __restrict__ Cout,
                                                 int M, int N, int K,
                                                 float scale_lo, int ncut) {
  __shared__ _Float16 As[128 * 64];
  __shared__ _Float16 Bs[128 * 64];
  const int t = threadIdx.x, w = t >> 6, lane = t & 63;
  const int m0 = blockIdx.y * 128, n0 = blockIdx.x * 128;
  const int wr = (w >> 1) * 64, wc = (w & 1) * 64;

  floatx4 acc[4][4] = {};

  for (int k0 = 0; k0 < K; k0 += 64) {
    __syncthreads();
#pragma unroll
    for (int i = 0; i < 4; i++) {
      int idx = t + 256 * i;
      int r = idx >> 3, c = idx & 7;
      int cs = c ^ (r & 7);
      gload16(A + (size_t)(m0 + r) * K + k0 + cs * 8, (char*)As + idx * 16);
      gload16(BT + (size_t)(n0 + r) * K + k0 + cs * 8, (char*)Bs + idx * 16);
    }
    __syncthreads();
#pragma unroll
    for (int ks = 0; ks < 2; ks++) {
      half8 af[4], bf[4];
#pragma unroll
      for (int r = 0; r < 4; r++) {
        int row = wr + r * 16 + (lane & 15);
        int ch = (ks * 4 + (lane >> 4)) ^ (row & 7);
        af[r] = *reinterpret_cast<const half8*>((const char*)As + row * 128 + ch * 16);
      }
#pragma unroll
      for (int c = 0; c < 4; c++) {
        int row = wc + c * 16 + (lane & 15);
        int ch = (ks * 4 + (lane >> 4)) ^ (row & 7);
        bf[c] = *reinterpret_cast<const half8*>((const char*)Bs + row * 128 + ch * 16);
      }
#pragma unroll
      for (int r = 0; r < 4; r++)
#pragma unroll
        for (int c = 0; c < 4; c++)
          acc[r][c] = __builtin_amdgcn_mfma_f32_16x16x32_f16(af[r], bf[c], acc[r][c], 0, 0, 0);
    }
  }

#pragma unroll
  for (int r = 0; r < 4; r++)
#pragma unroll
    for (int c = 0; c < 4; c++) {
      int col = n0 + wc + c * 16 + (lane & 15);
      float bv = bias[col];
      float sc = (col < ncut) ? scale_lo : 1.0f;
#pragma unroll
      for (int reg = 0; reg < 4; reg++) {
        int row = m0 + wr + r * 16 + (lane >> 4) * 4 + reg;
        float v = (acc[r][c][reg] + bv) * sc;
        if (OUT_HALF)
          reinterpret_cast<_Float16*>(Cout)[(size_t)row * N + col] = (_Float16)v;
        else
          reinterpret_cast<float*>(Cout)[(size_t)row * N + col] = v;
      }
    }
}

// ---------------------------------------------------------------------------
// V transpose: qkv[B*S][3D] fp16 (V slice) -> Vt[(b*H+h)*64 + d][S] fp16
// ---------------------------------------------------------------------------
__global__ __launch_bounds__(256) void v_transpose(const _Float16* __restrict__ qkv,
                                                   _Float16* __restrict__ Vt) {
  __shared__ _Float16 Vs[64][72];
  const int s0 = blockIdx.x * 64, bh = blockIdx.y;
  const int b = bh >> 4, h = bh & 15;
  const int t = threadIdx.x;
#pragma unroll
  for (int i = 0; i < 2; i++) {
    int idx = t + 256 * i;
    int r = idx >> 3, c = idx & 7;
    half8 v = *reinterpret_cast<const half8*>(
        qkv + (size_t)(b * S_ + s0 + r) * (3 * D_) + 2 * D_ + h * 64 + c * 8);
    *reinterpret_cast<half8*>(&Vs[r][c * 8]) = v;
  }
  __syncthreads();
#pragma unroll
  for (int i = 0; i < 2; i++) {
    int idx = t + 256 * i;
    int d = idx >> 3, c = idx & 7;
    half8 o;
#pragma unroll
    for (int j = 0; j < 8; j++) o[j] = Vs[c * 8 + j][d];
    *reinterpret_cast<half8*>(Vt + ((size_t)bh * 64 + d) * S_ + s0 + c * 8) = o;
  }
}

// ---------------------------------------------------------------------------
// Flash attention, fp16 MFMA 32x32x16, KVB=64 double-buffered, KV-SPLIT x2.
// (unchanged from R8 — race-proven)
// ---------------------------------------------------------------------------
__global__ __launch_bounds__(256, 3) void flash_mfma(const _Float16* __restrict__ qkv,
                                                     const _Float16* __restrict__ Vt,
                                                     _Float16* __restrict__ Opart,
                                                     float* __restrict__ keys) {
  const int qt = blockIdx.x, h = blockIdx.y;
  const int b = blockIdx.z >> 1, sp = blockIdx.z & 1;
  const int t = threadIdx.x, w = t >> 6, lane = t & 63;
  const int lo = lane & 31, hi = lane >> 5;

  __shared__ _Float16 Ks[2][KVB * 64];    // [kk][d] rows 128B, chunk^(r&7)
  __shared__ _Float16 Vts[2][64 * KVB];   // [d][kk] rows 128B, chunk^(r&7)

  const int qrow = qt * 128 + w * 32 + lo;
  const _Float16* qbase = qkv + (size_t)(b * S_ + qrow) * (3 * D_) + h * 64;
  half8 qf[4];
#pragma unroll
  for (int kd = 0; kd < 4; kd++)
    qf[kd] = *reinterpret_cast<const half8*>(qbase + kd * 16 + hi * 8);
  asm volatile("" : "+v"(qf[0]), "+v"(qf[1]), "+v"(qf[2]), "+v"(qf[3]));

  const size_t kbase = (size_t)(b * S_) * (3 * D_) + D_ + h * 64;
  const size_t vbase = (size_t)(b * H_ + h) * 64 * S_;
  const int kvbase = sp * (S_ / 2);

  auto stage = [&](int buf, int tile) {
    const int kv0 = kvbase + tile * KVB;
    const _Float16* kg = qkv + kbase + (size_t)kv0 * (3 * D_);
#pragma unroll
    for (int p = 0; p < 2; p++) {
      int idx = t + 256 * p;
      int r = idx >> 3, c = idx & 7, cs = c ^ (r & 7);
      gload16(kg + (size_t)r * (3 * D_) + cs * 8, (char*)&Ks[buf][0] + idx * 16);
    }
    const _Float16* vg = Vt + vbase + kv0;
#pragma unroll
    for (int p = 0; p < 2; p++) {
      int idx = t + 256 * p;
      int r = idx >> 3, c = idx & 7, cs = c ^ (r & 7);
      gload16(vg + (size_t)r * S_ + cs * 8, (char*)&Vts[buf][0] + idx * 16);
    }
  };

  floatx16 o0, o1;
#pragma unroll
  for (int r = 0; r < 16; r++) { o0[r] = 0.f; o1[r] = 0.f; }
  float m = -1e30f, l = 0.f;

  stage(0, 0);

  for (int tt = 0; tt < HT; ++tt) {
    const int cb = tt & 1;
    stage(cb ^ 1, (tt + 1) & (HT - 1));
    asm volatile("s_waitcnt vmcnt(4)" ::: "memory");
    __builtin_amdgcn_s_barrier();
    __builtin_amdgcn_sched_barrier(0);   // no ds_read hoist above the barrier

    const char* kb2 = (const char*)&Ks[cb][0];
    floatx16 s0v, s1v;
#pragma unroll
    for (int r = 0; r < 16; r++) { s0v[r] = 0.f; s1v[r] = 0.f; }
    __builtin_amdgcn_s_setprio(1);
#pragma unroll
    for (int kd = 0; kd < 4; kd++) {
      int r0 = lo, r1 = 32 + lo;
      half8 k0f = *reinterpret_cast<const half8*>(
          kb2 + r0 * 128 + (((kd * 2 + hi) ^ (r0 & 7)) * 16));
      half8 k1f = *reinterpret_cast<const half8*>(
          kb2 + r1 * 128 + (((kd * 2 + hi) ^ (r1 & 7)) * 16));
      s0v = __builtin_amdgcn_mfma_f32_32x32x16_f16(k0f, qf[kd], s0v, 0, 0, 0);
      s1v = __builtin_amdgcn_mfma_f32_32x32x16_f16(k1f, qf[kd], s1v, 0, 0, 0);
    }
    __builtin_amdgcn_s_setprio(0);

    float pm = -1e30f;
#pragma unroll
    for (int r = 0; r < 16; r++) pm = fmaxf(pm, fmaxf(s0v[r], s1v[r]));
    pm = fmaxf(pm, __shfl_xor(pm, 32));
    if (!__all(pm <= m + 8.0f)) {
      float mn = fmaxf(m, pm);
      float al = __builtin_amdgcn_exp2f(m - mn);
      m = mn; l *= al;
#pragma unroll
      for (int r = 0; r < 16; r++) { o0[r] *= al; o1[r] *= al; }
    }
    float rs = 0.f;
#pragma unroll
    for (int r = 0; r < 16; r++) {
      s0v[r] = __builtin_amdgcn_exp2f(s0v[r] - m);
      s1v[r] = __builtin_amdgcn_exp2f(s1v[r] - m);
      rs += s0v[r] + s1v[r];
    }
    rs += __shfl_xor(rs, 32);
    l += rs;

    half8 pf0a, pf0b, pf1a, pf1b;
    {
      unsigned a0 = __builtin_bit_cast(unsigned, __builtin_amdgcn_cvt_pkrtz(s0v[0], s0v[1]));
      unsigned b0 = __builtin_bit_cast(unsigned, __builtin_amdgcn_cvt_pkrtz(s0v[4], s0v[5]));
      unsigned a1 = __builtin_bit_cast(unsigned, __builtin_amdgcn_cvt_pkrtz(s0v[2], s0v[3]));
      unsigned b1 = __builtin_bit_cast(unsigned, __builtin_amdgcn_cvt_pkrtz(s0v[6], s0v[7]));
      asm("v_permlane32_swap_b32 %0, %1" : "+v"(a0), "+v"(b0));
      asm("v_permlane32_swap_b32 %0, %1" : "+v"(a1), "+v"(b1));
      uint4v u; u[0] = a0; u[1] = a1; u[2] = b0; u[3] = b1;
      pf0a = __builtin_bit_cast(half8, u);
      a0 = __builtin_bit_cast(unsigned, __builtin_amdgcn_cvt_pkrtz(s0v[8], s0v[9]));
      b0 = __builtin_bit_cast(unsigned, __builtin_amdgcn_cvt_pkrtz(s0v[12], s0v[13]));
      a1 = __builtin_bit_cast(unsigned, __builtin_amdgcn_cvt_pkrtz(s0v[10], s0v[11]));
      b1 = __builtin_bit_cast(unsigned, __builtin_amdgcn_cvt_pkrtz(s0v[14], s0v[15]));
      asm("v_permlane32_swap_b32 %0, %1" : "+v"(a0), "+v"(b0));
      asm("v_permlane32_swap_b32 %0, %1" : "+v"(a1), "+v"(b1));
      u[0] = a0; u[1] = a1; u[2] = b0; u[3] = b1;
      pf0b = __builtin_bit_cast(half8, u);
      a0 = __builtin_bit_cast(unsigned, __builtin_amdgcn_cvt_pkrtz(s1v[0], s1v[1]));
      b0 = __builtin_bit_cast(unsigned, __builtin_amdgcn_cvt_pkrtz(s1v[4], s1v[5]));
      a1 = __builtin_bit_cast(unsigned, __builtin_amdgcn_cvt_pkrtz(s1v[2], s1v[3]));
      b1 = __builtin_bit_cast(unsigned, __builtin_amdgcn_cvt_pkrtz(s1v[6], s1v[7]));
      asm("v_permlane32_swap_b32 %0, %1" : "+v"(a0), "+v"(b0));
      asm("v_permlane32_swap_b32 %0, %1" : "+v"(a1), "+v"(b1));
      u[0] = a0; u[1] = a1; u[2] = b0; u[3] = b1;
      pf1a = __builtin_bit_cast(half8, u);
      a0 = __builtin_bit_cast(unsigned, __builtin_amdgcn_cvt_pkrtz(s1v[8], s1v[9]));
      b0 = __builtin_bit_cast(unsigned, __builtin_amdgcn_cvt_pkrtz(s1v[12], s1v[13]));
      a1 = __builtin_bit_cast(unsigned, __builtin_amdgcn_cvt_pkrtz(s1v[10], s1v[11]));
      b1 = __builtin_bit_cast(unsigned, __builtin_amdgcn_cvt_pkrtz(s1v[14], s1v[15]));
      asm("v_permlane32_swap_b32 %0, %1" : "+v"(a0), "+v"(b0));
      asm("v_permlane32_swap_b32 %0, %1" : "+v"(a1), "+v"(b1));
      u[0] = a0; u[1] = a1; u[2] = b0; u[3] = b1;
      pf1b = __builtin_bit_cast(half8, u);
    }

    const char* vb2 = (const char*)&Vts[cb][0];
    __builtin_amdgcn_s_setprio(1);
#pragma unroll
    for (int ks = 0; ks < 4; ks++) {
      half8 pf = (ks == 0) ? pf0a : (ks == 1) ? pf0b : (ks == 2) ? pf1a : pf1b;
      const int ch = ks * 2 + hi;
      half8 vf0 = *reinterpret_cast<const half8*>(vb2 + lo * 128 + ((ch ^ (lo & 7)) * 16));
      half8 vf1 = *reinterpret_cast<const half8*>(vb2 + (lo + 32) * 128 + ((ch ^ (lo & 7)) * 16));
      o0 = __builtin_amdgcn_mfma_f32_32x32x16_f16(vf0, pf, o0, 0, 0, 0);
      o1 = __builtin_amdgcn_mfma_f32_32x32x16_f16(vf1, pf, o1, 0, 0, 0);
    }
    __builtin_amdgcn_s_setprio(0);

    __builtin_amdgcn_sched_barrier(0);   // no ds_read sink below the barrier
    __builtin_amdgcn_s_barrier();
  }

  float inv = 1.0f / l;
  const int gr = (b * H_ + h) * S_ + qrow;
  _Float16* ob = Opart + ((size_t)sp * NR_ + gr) * 64;
#pragma unroll
  for (int mt = 0; mt < 2; mt++)
#pragma unroll
    for (int rq = 0; rq < 4; rq++) {
      half4 v;
#pragma unroll
      for (int e = 0; e < 4; e++) v[e] = (_Float16)(((mt ? o1 : o0)[4 * rq + e]) * inv);
      *reinterpret_cast<half4*>(ob + 32 * mt + 8 * rq + 4 * hi) = v;
    }
  if (hi == 0) keys[sp * NR_ + gr] = m + __log2f(l);
}

// ---------------------------------------------------------------------------
// Combine the two KV-split halves: out = (w0*O0 + w1*O1)/(w0+w1), wi = 2^keyi
// ---------------------------------------------------------------------------
__global__ __launch_bounds__(256) void flash_combine(const _Float16* __restrict__ Opart,
                                                     const float* __restrict__ keys,
                                                     _Float16* __restrict__ attn_out) {
  const int gr = blockIdx.x * 256 + threadIdx.x;
  const float k0 = keys[gr], k1 = keys[NR_ + gr];
  const float mx = fmaxf(k0, k1);
  const float w0 = __builtin_amdgcn_exp2f(k0 - mx);
  const float w1 = __builtin_amdgcn_exp2f(k1 - mx);
  const float inv = 1.0f / (w0 + w1);
  const float a0 = w0 * inv, a1 = w1 * inv;
  const int bh = gr >> 11, qs = gr & 2047, b = bh >> 4, h = bh & 15;
  const half8* p0 = reinterpret_cast<const half8*>(Opart + (size_t)gr * 64);
  const half8* p1 = reinterpret_cast<const half8*>(Opart + ((size_t)NR_ + gr) * 64);
  half8* ob = reinterpret_cast<half8*>(
      attn_out + ((size_t)(b * S_ + qs)) * D_ + h * 64);
#pragma unroll
  for (int j = 0; j < 8; j++) {
    half8 x0 = p0[j], x1 = p1[j];
    half8 o;
#pragma unroll
    for (int e = 0; e < 8; e++)
      o[e] = (_Float16)(a0 * (float)x0[e] + a1 * (float)x1[e]);
    ob[j] = o;
  }
}

// ---------------------------------------------------------------------------
extern "C" void kernel_launch(void* const* d_in, const int* in_sizes, int n_in,
                              void* d_out, int out_size, void* d_ws, size_t ws_size,
                              hipStream_t stream) {
  const float* x     = (const float*)d_in[0];
  const float* W_qkv = (const float*)d_in[1];
  const float* b_qkv = (const float*)d_in[2];
  const float* W_out = (const float*)d_in[3];
  const float* b_out = (const float*)d_in[4];
  float* out = (float*)d_out;

  _Float16* xh    = (_Float16*)d_ws;
  _Float16* qkvh  = xh + (size_t)M_ * D_;
  _Float16* Vth   = qkvh + (size_t)M_ * 3 * D_;
  _Float16* WoT   = Vth + (size_t)B_ * H_ * 64 * S_;
  _Float16* WqT   = WoT + (size_t)D_ * D_;
  _Float16* Opart = WqT;                                  // alias (WqT dead by flash)
  float*    keys  = (float*)(Opart + (size_t)2 * NR_ * 64);
  _Float16* atth  = xh;                                   // alias (xh dead by combine)

  cast_f32_f16<<<(M_ * D_ / 8 + 255) / 256, 256, 0, stream>>>(x, xh, M_ * D_ / 8);
  transpose_cast2<<<dim3(3 * D_ / 64, D_ / 64, 2), 256, 0, stream>>>(
      W_qkv, WqT, W_out, WoT);

  // QKV projection: 256x192 tiles -> grid 16x16 = 256 blocks = full CU fill
  gemm256_mfma<<<256, 512, 114688, stream>>>(
      xh, WqT, b_qkv, qkvh, M_, 3 * D_, D_, QSCALE, D_);

  v_transpose<<<dim3(S_ / 64, B_ * H_), 256, 0, stream>>>(qkvh, Vth);

  flash_mfma<<<dim3(S_ / 128, H_, B_ * 2), 256, 0, stream>>>(qkvh, Vth, Opart, keys);

  flash_combine<<<NR_ / 256, 256, 0, stream>>>(Opart, keys, atth);

  gemm_mfma<false><<<dim3(D_ / 128, M_ / 128), 256, 0, stream>>>(
      atth, WoT, b_out, out, M_, D_, D_, 1.0f, 0);
}

// Round 10
// 135.062 us; speedup vs baseline: 1.1458x; 1.0147x over previous
//
#include <hip/hip_runtime.h>

typedef _Float16 half8  __attribute__((ext_vector_type(8)));
typedef _Float16 half4  __attribute__((ext_vector_type(4)));
typedef float    floatx4  __attribute__((ext_vector_type(4)));
typedef float    floatx16 __attribute__((ext_vector_type(16)));
typedef unsigned int uint4v __attribute__((ext_vector_type(4)));

constexpr int B_ = 2, S_ = 2048, D_ = 1024, H_ = 16, M_ = 4096;
constexpr int NR_ = B_ * H_ * S_;               // 65536 (b,h,s) rows
constexpr float QSCALE = 0.18033688011112042f;  // log2(e)/8
constexpr int KVB = 64;                         // kv tile
constexpr int HT = 16;                          // tiles per half (1024/64)

__device__ __forceinline__ void gload16(const void* g, void* l) {
  __builtin_amdgcn_global_load_lds((const __attribute__((address_space(1))) void*)g,
                                   (__attribute__((address_space(3))) void*)l, 16, 0, 0);
}

// ---------------------------------------------------------------------------
// cast fp32 -> fp16, 8 elems/thread
// ---------------------------------------------------------------------------
__global__ __launch_bounds__(256) void cast_f32_f16(const float* __restrict__ in,
                                                    _Float16* __restrict__ out, int n8) {
  int i = blockIdx.x * 256 + threadIdx.x;
  if (i >= n8) return;
  float4 a = reinterpret_cast<const float4*>(in)[2 * i];
  float4 b = reinterpret_cast<const float4*>(in)[2 * i + 1];
  half8 h;
  h[0] = (_Float16)a.x; h[1] = (_Float16)a.y; h[2] = (_Float16)a.z; h[3] = (_Float16)a.w;
  h[4] = (_Float16)b.x; h[5] = (_Float16)b.y; h[6] = (_Float16)b.z; h[7] = (_Float16)b.w;
  reinterpret_cast<half8*>(out)[i] = h;
}

// ---------------------------------------------------------------------------
// W[K][N] fp32 -> WT[N][K] fp16 (64x64 tiles). z selects {W_qkv, W_out}.
// ---------------------------------------------------------------------------
__global__ __launch_bounds__(256) void transpose_cast2(const float* __restrict__ W0,
                                                       _Float16* __restrict__ WT0,
                                                       const float* __restrict__ W1,
                                                       _Float16* __restrict__ WT1) {
  __shared__ float Ws[64][65];
  const int z = blockIdx.z;
  const int NW = z ? D_ : 3 * D_;
  if (blockIdx.x * 64 >= NW) return;
  const float* W = z ? W1 : W0;
  _Float16* WT = z ? WT1 : WT0;
  const int K = D_, N = NW;
  const int n0 = blockIdx.x * 64, k0 = blockIdx.y * 64;
  const int t = threadIdx.x;
#pragma unroll
  for (int i = 0; i < 4; i++) {
    int idx = t + 256 * i;
    int r = idx >> 4, c4 = idx & 15;
    float4 v = *reinterpret_cast<const float4*>(W + (size_t)(k0 + r) * N + n0 + c4 * 4);
    Ws[r][c4 * 4 + 0] = v.x; Ws[r][c4 * 4 + 1] = v.y;
    Ws[r][c4 * 4 + 2] = v.z; Ws[r][c4 * 4 + 3] = v.w;
  }
  __syncthreads();
#pragma unroll
  for (int i = 0; i < 2; i++) {
    int idx = t + 256 * i;
    int r = idx >> 3, ck = idx & 7;
    half8 h;
#pragma unroll
    for (int j = 0; j < 8; j++) h[j] = (_Float16)Ws[ck * 8 + j][r];
    *reinterpret_cast<half8*>(WT + (size_t)(n0 + r) * K + k0 + ck * 8) = h;
  }
}

// ---------------------------------------------------------------------------
// 256x192 fp16 MFMA GEMM, double-buffered, FINE-INTERLEAVED staging (m201).
// 512 thr = 8 waves (2M x 4N, 48 cols/wave); BK=64; 112 KiB LDS (dynamic).
// Per K-tile: vmcnt(0) (loads issued a full tile ago -> already landed) ->
// s_barrier+sched_barrier -> 4 quadrants {ds_read; ISSUE 1-2 next-tile
// global_load_lds; setprio MFMA} -> sched_barrier+s_barrier.
// Next-tile loads target the buffer freed by the PREVIOUS trailing barrier;
// sched_barrier(0) at both edges pins them inside the tile region (rule #18).
// ---------------------------------------------------------------------------
__global__ __launch_bounds__(512, 2) void gemm256_mfma(
    const _Float16* __restrict__ A, const _Float16* __restrict__ BT,
    const float* __restrict__ bias, _Float16* __restrict__ Cout,
    int M, int N, int K, float scale_lo, int ncut) {
  extern __shared__ char smem[];   // 114688 B: As[2][32K] | Bs[2][24K]
  const int tid = threadIdx.x, w = tid >> 6, lane = tid & 63;
  const int wm = w >> 2, wn = w & 3;

  // XCD-aware bijective swizzle over flat grid (nwg = 256, % 8 == 0)
  const int nwg = gridDim.x, cpx = nwg >> 3;
  const int wg = (blockIdx.x & 7) * cpx + (blockIdx.x >> 3);
  const int nbx = N / 192;
  const int bx = wg % nbx, by = wg / nbx;
  const int m0 = by * 256, n0 = bx * 192;

  const int NT = K >> 6;

  auto stageA1 = [&](int buf, int kt, int i) {   // one A load (i in 0..3)
    const int k0 = kt * 64;
    char* Ad = smem + buf * 32768;
    int idx = tid + 512 * i;
    int r = idx >> 3, c = idx & 7, cs = c ^ (r & 7);
    gload16(A + (size_t)(m0 + r) * K + k0 + cs * 8, Ad + idx * 16);
  };
  auto stageB1 = [&](int buf, int kt, int i) {   // one B load (i in 0..2)
    const int k0 = kt * 64;
    char* Bd = smem + 65536 + buf * 24576;
    int idx = tid + 512 * i;
    int r = idx >> 3, c = idx & 7, cs = c ^ (r & 7);
    gload16(BT + (size_t)(n0 + r) * K + k0 + cs * 8, Bd + idx * 16);
  };

  floatx4 acc[8][3] = {};

  // prologue: tile 0 full stage
#pragma unroll
  for (int i = 0; i < 4; i++) stageA1(0, 0, i);
#pragma unroll
  for (int i = 0; i < 3; i++) stageB1(0, 0, i);

  for (int kt = 0; kt < NT; ++kt) {
    const int p = kt & 1;
    asm volatile("s_waitcnt vmcnt(0)" ::: "memory");  // tile kt landed (issued 1 tile ago)
    __builtin_amdgcn_s_barrier();
    __builtin_amdgcn_sched_barrier(0);   // no ds_read hoist above the barrier

    const char* Ab = smem + p * 32768;
    const char* Bb = smem + 65536 + p * 24576;
    const bool more = (kt + 1 < NT);
#pragma unroll
    for (int q = 0; q < 4; q++) {
      half8 af[2][2], bf[3][2];
#pragma unroll
      for (int e = 0; e < 2; e++)
#pragma unroll
        for (int ks = 0; ks < 2; ks++) {
          int row = wm * 128 + (2 * q + e) * 16 + (lane & 15);
          int ch = (ks * 4 + (lane >> 4)) ^ (row & 7);
          af[e][ks] = *reinterpret_cast<const half8*>(Ab + row * 128 + ch * 16);
        }
#pragma unroll
      for (int n = 0; n < 3; n++)
#pragma unroll
        for (int ks = 0; ks < 2; ks++) {
          int row = wn * 48 + n * 16 + (lane & 15);
          int ch = (ks * 4 + (lane >> 4)) ^ (row & 7);
          bf[n][ks] = *reinterpret_cast<const half8*>(Bb + row * 128 + ch * 16);
        }
      // fine-interleaved next-tile staging: 2A / 2A / 2B / 1B per quadrant
      if (more) {
        if (q == 0)      { stageA1(p ^ 1, kt + 1, 0); stageA1(p ^ 1, kt + 1, 1); }
        else if (q == 1) { stageA1(p ^ 1, kt + 1, 2); stageA1(p ^ 1, kt + 1, 3); }
        else if (q == 2) { stageB1(p ^ 1, kt + 1, 0); stageB1(p ^ 1, kt + 1, 1); }
        else             { stageB1(p ^ 1, kt + 1, 2); }
      }
      __builtin_amdgcn_s_setprio(1);
#pragma unroll
      for (int ks = 0; ks < 2; ks++)
#pragma unroll
        for (int e = 0; e < 2; e++)
#pragma unroll
          for (int n = 0; n < 3; n++)
            acc[2 * q + e][n] = __builtin_amdgcn_mfma_f32_16x16x32_f16(
                af[e][ks], bf[n][ks], acc[2 * q + e][n], 0, 0, 0);
      __builtin_amdgcn_s_setprio(0);
    }
    __builtin_amdgcn_sched_barrier(0);   // no ds_read sink below the barrier
    __builtin_amdgcn_s_barrier();        // all reads of buffer p done before overwrite
  }

#pragma unroll
  for (int mf = 0; mf < 8; mf++)
#pragma unroll
    for (int n = 0; n < 3; n++) {
      int col = n0 + wn * 48 + n * 16 + (lane & 15);
      float bv = bias[col];
      float sc = (col < ncut) ? scale_lo : 1.0f;
#pragma unroll
      for (int reg = 0; reg < 4; reg++) {
        int row = m0 + wm * 128 + mf * 16 + (lane >> 4) * 4 + reg;
        Cout[(size_t)row * N + col] = (_Float16)((acc[mf][n][reg] + bv) * sc);
      }
    }
}

// ---------------------------------------------------------------------------
// fp16 MFMA GEMM, 128x128 tile (m97-class) — used for the output projection
// ---------------------------------------------------------------------------
template <bool OUT_HALF>
__global__ __launch_bounds__(256) void gemm_mfma(const _Float16* __restrict__ A,
                                                 const _Float16* __restrict__ BT,
                                                 const float* __restrict__ bias,
                                                 void* __restrict__ Cout,
                                                 int M, int N, int K,
                                                 float scale_lo, int ncut) {
  __shared__ _Float16 As[128 * 64];
  __shared__ _Float16 Bs[128 * 64];
  const int t = threadIdx.x, w = t >> 6, lane = t & 63;
  const int m0 = blockIdx.y * 128, n0 = blockIdx.x * 128;
  const int wr = (w >> 1) * 64, wc = (w & 1) * 64;

  floatx4 acc[4][4] = {};

  for (int k0 = 0; k0 < K; k0 += 64) {
    __syncthreads();
#pragma unroll
    for (int i = 0; i < 4; i++) {
      int idx = t + 256 * i;
      int r = idx >> 3, c = idx & 7;
      int cs = c ^ (r & 7);
      gload16(A + (size_t)(m0 + r) * K + k0 + cs * 8, (char*)As + idx * 16);
      gload16(BT + (size_t)(n0 + r) * K + k0 + cs * 8, (char*)Bs + idx * 16);
    }
    __syncthreads();
#pragma unroll
    for (int ks = 0; ks < 2; ks++) {
      half8 af[4], bf[4];
#pragma unroll
      for (int r = 0; r < 4; r++) {
        int row = wr + r * 16 + (lane & 15);
        int ch = (ks * 4 + (lane >> 4)) ^ (row & 7);
        af[r] = *reinterpret_cast<const half8*>((const char*)As + row * 128 + ch * 16);
      }
#pragma unroll
      for (int c = 0; c < 4; c++) {
        int row = wc + c * 16 + (lane & 15);
        int ch = (ks * 4 + (lane >> 4)) ^ (row & 7);
        bf[c] = *reinterpret_cast<const half8*>((const char*)Bs + row * 128 + ch * 16);
      }
#pragma unroll
      for (int r = 0; r < 4; r++)
#pragma unroll
        for (int c = 0; c < 4; c++)
          acc[r][c] = __builtin_amdgcn_mfma_f32_16x16x32_f16(af[r], bf[c], acc[r][c], 0, 0, 0);
    }
  }

#pragma unroll
  for (int r = 0; r < 4; r++)
#pragma unroll
    for (int c = 0; c < 4; c++) {
      int col = n0 + wc + c * 16 + (lane & 15);
      float bv = bias[col];
      float sc = (col < ncut) ? scale_lo : 1.0f;
#pragma unroll
      for (int reg = 0; reg < 4; reg++) {
        int row = m0 + wr + r * 16 + (lane >> 4) * 4 + reg;
        float v = (acc[r][c][reg] + bv) * sc;
        if (OUT_HALF)
          reinterpret_cast<_Float16*>(Cout)[(size_t)row * N + col] = (_Float16)v;
        else
          reinterpret_cast<float*>(Cout)[(size_t)row * N + col] = v;
      }
    }
}

// ---------------------------------------------------------------------------
// V transpose: qkv[B*S][3D] fp16 (V slice) -> Vt[(b*H+h)*64 + d][S] fp16
// ---------------------------------------------------------------------------
__global__ __launch_bounds__(256) void v_transpose(const _Float16* __restrict__ qkv,
                                                   _Float16* __restrict__ Vt) {
  __shared__ _Float16 Vs[64][72];
  const int s0 = blockIdx.x * 64, bh = blockIdx.y;
  const int b = bh >> 4, h = bh & 15;
  const int t = threadIdx.x;
#pragma unroll
  for (int i = 0; i < 2; i++) {
    int idx = t + 256 * i;
    int r = idx >> 3, c = idx & 7;
    half8 v = *reinterpret_cast<const half8*>(
        qkv + (size_t)(b * S_ + s0 + r) * (3 * D_) + 2 * D_ + h * 64 + c * 8);
    *reinterpret_cast<half8*>(&Vs[r][c * 8]) = v;
  }
  __syncthreads();
#pragma unroll
  for (int i = 0; i < 2; i++) {
    int idx = t + 256 * i;
    int d = idx >> 3, c = idx & 7;
    half8 o;
#pragma unroll
    for (int j = 0; j < 8; j++) o[j] = Vs[c * 8 + j][d];
    *reinterpret_cast<half8*>(Vt + ((size_t)bh * 64 + d) * S_ + s0 + c * 8) = o;
  }
}

// ---------------------------------------------------------------------------
// Flash attention, fp16 MFMA 32x32x16, KVB=64 double-buffered, KV-SPLIT x2.
// R10: launch_bounds (256,3)->(256,4). VGPR=60 <= 128-cap, LDS 32K x4 = 128K
// -> 4 blocks/CU (grid-limited), 16 waves/CU. Everything else race-proven R8.
// ---------------------------------------------------------------------------
__global__ __launch_bounds__(256, 4) void flash_mfma(const _Float16* __restrict__ qkv,
                                                     const _Float16* __restrict__ Vt,
                                                     _Float16* __restrict__ Opart,
                                                     float* __restrict__ keys) {
  const int qt = blockIdx.x, h = blockIdx.y;
  const int b = blockIdx.z >> 1, sp = blockIdx.z & 1;
  const int t = threadIdx.x, w = t >> 6, lane = t & 63;
  const int lo = lane & 31, hi = lane >> 5;

  __shared__ _Float16 Ks[2][KVB * 64];    // [kk][d] rows 128B, chunk^(r&7)
  __shared__ _Float16 Vts[2][64 * KVB];   // [d][kk] rows 128B, chunk^(r&7)

  const int qrow = qt * 128 + w * 32 + lo;
  const _Float16* qbase = qkv + (size_t)(b * S_ + qrow) * (3 * D_) + h * 64;
  half8 qf[4];
#pragma unroll
  for (int kd = 0; kd < 4; kd++)
    qf[kd] = *reinterpret_cast<const half8*>(qbase + kd * 16 + hi * 8);
  asm volatile("" : "+v"(qf[0]), "+v"(qf[1]), "+v"(qf[2]), "+v"(qf[3]));

  const size_t kbase = (size_t)(b * S_) * (3 * D_) + D_ + h * 64;
  const size_t vbase = (size_t)(b * H_ + h) * 64 * S_;
  const int kvbase = sp * (S_ / 2);

  auto stage = [&](int buf, int tile) {
    const int kv0 = kvbase + tile * KVB;
    const _Float16* kg = qkv + kbase + (size_t)kv0 * (3 * D_);
#pragma unroll
    for (int p = 0; p < 2; p++) {
      int idx = t + 256 * p;
      int r = idx >> 3, c = idx & 7, cs = c ^ (r & 7);
      gload16(kg + (size_t)r * (3 * D_) + cs * 8, (char*)&Ks[buf][0] + idx * 16);
    }
    const _Float16* vg = Vt + vbase + kv0;
#pragma unroll
    for (int p = 0; p < 2; p++) {
      int idx = t + 256 * p;
      int r = idx >> 3, c = idx & 7, cs = c ^ (r & 7);
      gload16(vg + (size_t)r * S_ + cs * 8, (char*)&Vts[buf][0] + idx * 16);
    }
  };

  floatx16 o0, o1;
#pragma unroll
  for (int r = 0; r < 16; r++) { o0[r] = 0.f; o1[r] = 0.f; }
  float m = -1e30f, l = 0.f;

  stage(0, 0);

  for (int tt = 0; tt < HT; ++tt) {
    const int cb = tt & 1;
    stage(cb ^ 1, (tt + 1) & (HT - 1));
    asm volatile("s_waitcnt vmcnt(4)" ::: "memory");
    __builtin_amdgcn_s_barrier();
    __builtin_amdgcn_sched_barrier(0);   // no ds_read hoist above the barrier

    const char* kb2 = (const char*)&Ks[cb][0];
    floatx16 s0v, s1v;
#pragma unroll
    for (int r = 0; r < 16; r++) { s0v[r] = 0.f; s1v[r] = 0.f; }
    __builtin_amdgcn_s_setprio(1);
#pragma unroll
    for (int kd = 0; kd < 4; kd++) {
      int r0 = lo, r1 = 32 + lo;
      half8 k0f = *reinterpret_cast<const half8*>(
          kb2 + r0 * 128 + (((kd * 2 + hi) ^ (r0 & 7)) * 16));
      half8 k1f = *reinterpret_cast<const half8*>(
          kb2 + r1 * 128 + (((kd * 2 + hi) ^ (r1 & 7)) * 16));
      s0v = __builtin_amdgcn_mfma_f32_32x32x16_f16(k0f, qf[kd], s0v, 0, 0, 0);
      s1v = __builtin_amdgcn_mfma_f32_32x32x16_f16(k1f, qf[kd], s1v, 0, 0, 0);
    }
    __builtin_amdgcn_s_setprio(0);

    float pm = -1e30f;
#pragma unroll
    for (int r = 0; r < 16; r++) pm = fmaxf(pm, fmaxf(s0v[r], s1v[r]));
    pm = fmaxf(pm, __shfl_xor(pm, 32));
    if (!__all(pm <= m + 8.0f)) {
      float mn = fmaxf(m, pm);
      float al = __builtin_amdgcn_exp2f(m - mn);
      m = mn; l *= al;
#pragma unroll
      for (int r = 0; r < 16; r++) { o0[r] *= al; o1[r] *= al; }
    }
    float rs = 0.f;
#pragma unroll
    for (int r = 0; r < 16; r++) {
      s0v[r] = __builtin_amdgcn_exp2f(s0v[r] - m);
      s1v[r] = __builtin_amdgcn_exp2f(s1v[r] - m);
      rs += s0v[r] + s1v[r];
    }
    rs += __shfl_xor(rs, 32);
    l += rs;

    half8 pf0a, pf0b, pf1a, pf1b;
    {
      unsigned a0 = __builtin_bit_cast(unsigned, __builtin_amdgcn_cvt_pkrtz(s0v[0], s0v[1]));
      unsigned b0 = __builtin_bit_cast(unsigned, __builtin_amdgcn_cvt_pkrtz(s0v[4], s0v[5]));
      unsigned a1 = __builtin_bit_cast(unsigned, __builtin_amdgcn_cvt_pkrtz(s0v[2], s0v[3]));
      unsigned b1 = __builtin_bit_cast(unsigned, __builtin_amdgcn_cvt_pkrtz(s0v[6], s0v[7]));
      asm("v_permlane32_swap_b32 %0, %1" : "+v"(a0), "+v"(b0));
      asm("v_permlane32_swap_b32 %0, %1" : "+v"(a1), "+v"(b1));
      uint4v u; u[0] = a0; u[1] = a1; u[2] = b0; u[3] = b1;
      pf0a = __builtin_bit_cast(half8, u);
      a0 = __builtin_bit_cast(unsigned, __builtin_amdgcn_cvt_pkrtz(s0v[8], s0v[9]));
      b0 = __builtin_bit_cast(unsigned, __builtin_amdgcn_cvt_pkrtz(s0v[12], s0v[13]));
      a1 = __builtin_bit_cast(unsigned, __builtin_amdgcn_cvt_pkrtz(s0v[10], s0v[11]));
      b1 = __builtin_bit_cast(unsigned, __builtin_amdgcn_cvt_pkrtz(s0v[14], s0v[15]));
      asm("v_permlane32_swap_b32 %0, %1" : "+v"(a0), "+v"(b0));
      asm("v_permlane32_swap_b32 %0, %1" : "+v"(a1), "+v"(b1));
      u[0] = a0; u[1] = a1; u[2] = b0; u[3] = b1;
      pf0b = __builtin_bit_cast(half8, u);
      a0 = __builtin_bit_cast(unsigned, __builtin_amdgcn_cvt_pkrtz(s1v[0], s1v[1]));
      b0 = __builtin_bit_cast(unsigned, __builtin_amdgcn_cvt_pkrtz(s1v[4], s1v[5]));
      a1 = __builtin_bit_cast(unsigned, __builtin_amdgcn_cvt_pkrtz(s1v[2], s1v[3]));
      b1 = __builtin_bit_cast(unsigned, __builtin_amdgcn_cvt_pkrtz(s1v[6], s1v[7]));
      asm("v_permlane32_swap_b32 %0, %1" : "+v"(a0), "+v"(b0));
      asm("v_permlane32_swap_b32 %0, %1" : "+v"(a1), "+v"(b1));
      u[0] = a0; u[1] = a1; u[2] = b0; u[3] = b1;
      pf1a = __builtin_bit_cast(half8, u);
      a0 = __builtin_bit_cast(unsigned, __builtin_amdgcn_cvt_pkrtz(s1v[8], s1v[9]));
      b0 = __builtin_bit_cast(unsigned, __builtin_amdgcn_cvt_pkrtz(s1v[12], s1v[13]));
      a1 = __builtin_bit_cast(unsigned, __builtin_amdgcn_cvt_pkrtz(s1v[10], s1v[11]));
      b1 = __builtin_bit_cast(unsigned, __builtin_amdgcn_cvt_pkrtz(s1v[14], s1v[15]));
      asm("v_permlane32_swap_b32 %0, %1" : "+v"(a0), "+v"(b0));
      asm("v_permlane32_swap_b32 %0, %1" : "+v"(a1), "+v"(b1));
      u[0] = a0; u[1] = a1; u[2] = b0; u[3] = b1;
      pf1b = __builtin_bit_cast(half8, u);
    }

    const char* vb2 = (const char*)&Vts[cb][0];
    __builtin_amdgcn_s_setprio(1);
#pragma unroll
    for (int ks = 0; ks < 4; ks++) {
      half8 pf = (ks == 0) ? pf0a : (ks == 1) ? pf0b : (ks == 2) ? pf1a : pf1b;
      const int ch = ks * 2 + hi;
      half8 vf0 = *reinterpret_cast<const half8*>(vb2 + lo * 128 + ((ch ^ (lo & 7)) * 16));
      half8 vf1 = *reinterpret_cast<const half8*>(vb2 + (lo + 32) * 128 + ((ch ^ (lo & 7)) * 16));
      o0 = __builtin_amdgcn_mfma_f32_32x32x16_f16(vf0, pf, o0, 0, 0, 0);
      o1 = __builtin_amdgcn_mfma_f32_32x32x16_f16(vf1, pf, o1, 0, 0, 0);
    }
    __builtin_amdgcn_s_setprio(0);

    __builtin_amdgcn_sched_barrier(0);   // no ds_read sink below the barrier
    __builtin_amdgcn_s_barrier();
  }

  float inv = 1.0f / l;
  const int gr = (b * H_ + h) * S_ + qrow;
  _Float16* ob = Opart + ((size_t)sp * NR_ + gr) * 64;
#pragma unroll
  for (int mt = 0; mt < 2; mt++)
#pragma unroll
    for (int rq = 0; rq < 4; rq++) {
      half4 v;
#pragma unroll
      for (int e = 0; e < 4; e++) v[e] = (_Float16)(((mt ? o1 : o0)[4 * rq + e]) * inv);
      *reinterpret_cast<half4*>(ob + 32 * mt + 8 * rq + 4 * hi) = v;
    }
  if (hi == 0) keys[sp * NR_ + gr] = m + __log2f(l);
}

// ---------------------------------------------------------------------------
// Combine the two KV-split halves: out = (w0*O0 + w1*O1)/(w0+w1), wi = 2^keyi
// ---------------------------------------------------------------------------
__global__ __launch_bounds__(256) void flash_combine(const _Float16* __restrict__ Opart,
                                                     const float* __restrict__ keys,
                                                     _Float16* __restrict__ attn_out) {
  const int gr = blockIdx.x * 256 + threadIdx.x;
  const float k0 = keys[gr], k1 = keys[NR_ + gr];
  const float mx = fmaxf(k0, k1);
  const float w0 = __builtin_amdgcn_exp2f(k0 - mx);
  const float w1 = __builtin_amdgcn_exp2f(k1 - mx);
  const float inv = 1.0f / (w0 + w1);
  const float a0 = w0 * inv, a1 = w1 * inv;
  const int bh = gr >> 11, qs = gr & 2047, b = bh >> 4, h = bh & 15;
  const half8* p0 = reinterpret_cast<const half8*>(Opart + (size_t)gr * 64);
  const half8* p1 = reinterpret_cast<const half8*>(Opart + ((size_t)NR_ + gr) * 64);
  half8* ob = reinterpret_cast<half8*>(
      attn_out + ((size_t)(b * S_ + qs)) * D_ + h * 64);
#pragma unroll
  for (int j = 0; j < 8; j++) {
    half8 x0 = p0[j], x1 = p1[j];
    half8 o;
#pragma unroll
    for (int e = 0; e < 8; e++)
      o[e] = (_Float16)(a0 * (float)x0[e] + a1 * (float)x1[e]);
    ob[j] = o;
  }
}

// ---------------------------------------------------------------------------
extern "C" void kernel_launch(void* const* d_in, const int* in_sizes, int n_in,
                              void* d_out, int out_size, void* d_ws, size_t ws_size,
                              hipStream_t stream) {
  const float* x     = (const float*)d_in[0];
  const float* W_qkv = (const float*)d_in[1];
  const float* b_qkv = (const float*)d_in[2];
  const float* W_out = (const float*)d_in[3];
  const float* b_out = (const float*)d_in[4];
  float* out = (float*)d_out;

  _Float16* xh    = (_Float16*)d_ws;
  _Float16* qkvh  = xh + (size_t)M_ * D_;
  _Float16* Vth   = qkvh + (size_t)M_ * 3 * D_;
  _Float16* WoT   = Vth + (size_t)B_ * H_ * 64 * S_;
  _Float16* WqT   = WoT + (size_t)D_ * D_;
  _Float16* Opart = WqT;                                  // alias (WqT dead by flash)
  float*    keys  = (float*)(Opart + (size_t)2 * NR_ * 64);
  _Float16* atth  = xh;                                   // alias (xh dead by combine)

  cast_f32_f16<<<(M_ * D_ / 8 + 255) / 256, 256, 0, stream>>>(x, xh, M_ * D_ / 8);
  transpose_cast2<<<dim3(3 * D_ / 64, D_ / 64, 2), 256, 0, stream>>>(
      W_qkv, WqT, W_out, WoT);

  // QKV projection: 256x192 tiles -> grid 16x16 = 256 blocks = full CU fill
  gemm256_mfma<<<256, 512, 114688, stream>>>(
      xh, WqT, b_qkv, qkvh, M_, 3 * D_, D_, QSCALE, D_);

  v_transpose<<<dim3(S_ / 64, B_ * H_), 256, 0, stream>>>(qkvh, Vth);

  flash_mfma<<<dim3(S_ / 128, H_, B_ * 2), 256, 0, stream>>>(qkvh, Vth, Opart, keys);

  flash_combine<<<NR_ / 256, 256, 0, stream>>>(Opart, keys, atth);

  gemm_mfma<false><<<dim3(D_ / 128, M_ / 128), 256, 0, stream>>>(
      atth, WoT, b_out, out, M_, D_, D_, 1.0f, 0);
}